// Round 7
// baseline (440.867 us; speedup 1.0000x reference)
//
#include <hip/hip_runtime.h>
#include <math.h>

typedef unsigned short ushort_t;
typedef __attribute__((ext_vector_type(8))) short bf16x8;
typedef __attribute__((ext_vector_type(4))) float f32x4;

__device__ __forceinline__ ushort_t f2bf(float f) {
  unsigned u = __float_as_uint(f);
  unsigned r = (u + 0x7FFF + ((u >> 16) & 1)) >> 16;  // RNE
  return (ushort_t)r;
}
__device__ __forceinline__ float bf2f(ushort_t u) {
  return __uint_as_float(((unsigned)u) << 16);
}

__device__ __forceinline__ void gload_lds16(const void* g, void* l) {
  __builtin_amdgcn_global_load_lds(
      (const __attribute__((address_space(1))) void*)g,
      (__attribute__((address_space(3))) void*)l, 16, 0, 0);
}

// counted-vmcnt barrier: wait own staging loads (vmcnt<=N), then sync all waves.
#define PIPE_BAR(N)                                          \
  do {                                                       \
    asm volatile("s_waitcnt vmcnt(" #N ")" ::: "memory");    \
    __builtin_amdgcn_s_barrier();                            \
    asm volatile("" ::: "memory");                           \
  } while (0)

// ---------------------------------------------------------------- init: cursor=1, zero s/d buffers
__global__ void init_k(int* __restrict__ cursor, int n, float* __restrict__ z, int nz) {
  int i = blockIdx.x * blockDim.x + threadIdx.x;
  if (i < n) cursor[i] = 1;  // self-loop contributes 1 to in-degree
  if (i < nz) z[i] = 0.f;
}

__global__ void count_edges_k(const int* __restrict__ dst, int E, int* __restrict__ cnt) {
  int i = blockIdx.x * blockDim.x + threadIdx.x;
  if (i < E) atomicAdd(&cnt[dst[i]], 1);
}

// exclusive scan; writes indptr AND cursor
__global__ void scan_k(const int* __restrict__ cnt, int* __restrict__ indptr,
                       int* __restrict__ cursor, int n) {
  __shared__ int lds[1024];
  __shared__ int carry_s;
  int t = threadIdx.x;
  if (t == 0) carry_s = 0;
  __syncthreads();
  for (int base = 0; base < n; base += 1024) {
    int i = base + t;
    int v = (i < n) ? cnt[i] : 0;
    lds[t] = v;
    __syncthreads();
    for (int off = 1; off < 1024; off <<= 1) {
      int add = (t >= off) ? lds[t - off] : 0;
      __syncthreads();
      lds[t] += add;
      __syncthreads();
    }
    int carry = carry_s;
    if (i < n) { int e = carry + lds[t] - v; indptr[i] = e; cursor[i] = e; }
    __syncthreads();
    if (t == 1023) carry_s = carry + lds[1023];
    __syncthreads();
  }
  if (t == 0) indptr[n] = carry_s;
}

__global__ void scatter_k(const int* __restrict__ src, const int* __restrict__ dst, int E, int n,
                          int* __restrict__ cursor, int* __restrict__ esrc) {
  int i = blockIdx.x * blockDim.x + threadIdx.x;
  if (i < E) {
    int p = atomicAdd(&cursor[dst[i]], 1);
    esrc[p] = src[i];
  } else if (i < E + n) {
    int node = i - E;
    int p = atomicAdd(&cursor[node], 1);
    esrc[p] = node;  // self loop
  }
}

// ---------------------------------------------------------------- conversions
__global__ void cast_bf16_k(const float* __restrict__ in, ushort_t* __restrict__ out, int n4) {
  int i = blockIdx.x * blockDim.x + threadIdx.x;
  if (i < n4) {
    float4 v = ((const float4*)in)[i];
    ushort_t o0 = f2bf(v.x), o1 = f2bf(v.y), o2 = f2bf(v.z), o3 = f2bf(v.w);
    ushort_t* p = out + i * 4;
    p[0] = o0; p[1] = o1; p[2] = o2; p[3] = o3;
  }
}

// Two fp32 [K][Na],[K][Nb] -> one bf16 [Na+Nb][K] (concatenated transpose).
__global__ __launch_bounds__(256) void transpose_dual_k(const float* __restrict__ Wa, int Na,
                                                        const float* __restrict__ Wb, int Nb,
                                                        int K, ushort_t* __restrict__ dst) {
  __shared__ float tile[32][33];
  const int bx = blockIdx.x * 32;  // n dim (global, 0..Na+Nb)
  const int by = blockIdx.y * 32;  // k dim
  const int tx = threadIdx.x & 31, ty = threadIdx.x >> 5;  // 32x8
  const bool isB = bx >= Na;       // blocks are 32-aligned; Na is a multiple of 32
  const float* W = isB ? Wb : Wa;
  const int Nw = isB ? Nb : Na;
  const int nc = bx - (isB ? Na : 0) + tx;
  for (int i = ty; i < 32; i += 8)
    tile[i][tx] = W[(size_t)(by + i) * Nw + nc];
  __syncthreads();
  for (int i = ty; i < 32; i += 8)
    dst[(size_t)(bx + i) * K + by + tx] = f2bf(tile[tx][i]);
}

// Fold a3 into W3cat pad rows: row 448+hd = W3 . a3s[hd], row 454+hd = W3 . a3d[hd].
__global__ void fold_a3_k(const float* __restrict__ W3, const float* __restrict__ a3s,
                          const float* __restrict__ a3d, ushort_t* __restrict__ W3cat) {
  int k = blockIdx.x * blockDim.x + threadIdx.x;  // 0..1023
  if (k >= 1024) return;
  const float* row = W3 + (size_t)k * 384;
  for (int hd = 0; hd < 6; ++hd) {
    float ss = 0.f, dd = 0.f;
    for (int c = 0; c < 64; ++c) {
      float w = row[hd * 64 + c];
      ss += w * a3s[hd * 64 + c];
      dd += w * a3d[hd * 64 + c];
    }
    W3cat[(size_t)(448 + hd) * 1024 + k] = f2bf(ss);
    W3cat[(size_t)(454 + hd) * 1024 + k] = f2bf(dd);
  }
  for (int j = 460; j < 512; ++j) W3cat[(size_t)j * 1024 + k] = 0;
}

// ---------------------------------------------------------------- 256x256 8-wave phase-split GEMM
// BM=BN=256, BK=64, 512 thr (8 waves 2x4). Per K-tile: 2 phases (kk halves).
// Phase: 12 ds_read_b128 || stage next tile's matching k-half (4 gload_lds) ||
// setprio+32 MFMA, then vmcnt(4)+s_barrier (loads span barriers; drain only at tail).
// LDS 128 KB: [buf][kk][256 rows][4 slots of 16B], XOR-swizzled slot = g ^ ((row>>1)&3).
template<int NCT, int HC, int SC, bool LOGITS, bool SKIP_BF16>
__global__ __launch_bounds__(512, 2) void gemm256(const ushort_t* __restrict__ A,
                                                  const ushort_t* __restrict__ BT,
                                                  const float* __restrict__ skip_bias,
                                                  const float* __restrict__ a_src,
                                                  const float* __restrict__ a_dst,
                                                  float* __restrict__ sb,
                                                  float* __restrict__ db,
                                                  ushort_t* __restrict__ h_out,
                                                  void* __restrict__ skip_out,
                                                  int M, int K) {
  __shared__ ushort_t As[4 * 8192];  // 64 KB: (buf*2+kk)*8192 + row*32 + slot*8
  __shared__ ushort_t Bs[4 * 8192];  // 64 KB
  const int gx = gridDim.x;
  const int nwg = gx * (int)gridDim.y;
  const int orig = blockIdx.y * gx + blockIdx.x;
  const int q = nwg >> 3, r = nwg & 7, xcd = orig & 7;
  const int wgid = (xcd < r ? xcd * (q + 1) : r * (q + 1) + (xcd - r) * q) + (orig >> 3);
  const int bm = (wgid / gx) * 256, bn = (wgid % gx) * 256;

  const int t = threadIdx.x, l = t & 63, wid = t >> 6;
  const int wm = wid >> 2, wn = wid & 3;      // wave grid 2 (M) x 4 (N)
  const int lr = l & 15, s4 = l >> 4;

  // staging source (call c covers rows c*128..c*128+127; thread -> row=(t>>2), slot=t&3)
  int gsrcA[2], gsrcB[2];
  for (int c = 0; c < 2; ++c) {
    int row = c * 128 + (t >> 2);
    int sl = (t & 3) ^ ((row >> 1) & 3);  // inverse-swizzled source slot
    gsrcA[c] = min(bm + row, M - 1) * K + sl * 8;
    gsrcB[c] = min(bn + row, NCT - 1) * K + sl * 8;
  }
  // fragment read offsets (ushort idx within one (buf,kk) region)
  int roffA[8], roffB[4];
#pragma unroll
  for (int m = 0; m < 8; ++m) {
    int ra = wm * 128 + m * 16 + lr;
    roffA[m] = ra * 32 + ((s4 ^ ((ra >> 1) & 3)) * 8);
  }
#pragma unroll
  for (int n = 0; n < 4; ++n) {
    int rb = wn * 64 + n * 16 + lr;
    roffB[n] = rb * 32 + ((s4 ^ ((rb >> 1) & 3)) * 8);
  }

  f32x4 acc[8][4] = {};

  auto stage_half = [&](int tile, int kk) {  // 4 gload_lds calls (A c0,c1; B c0,c1)
    const int buf = tile & 1;
    const int kbase = tile * 64 + kk * 32;
    ushort_t* da = &As[(buf * 2 + kk) * 8192 + wid * 512];
    ushort_t* dbp = &Bs[(buf * 2 + kk) * 8192 + wid * 512];
    gload_lds16(A + gsrcA[0] + kbase, da);
    gload_lds16(A + gsrcA[1] + kbase, da + 4096);
    gload_lds16(BT + gsrcB[0] + kbase, dbp);
    gload_lds16(BT + gsrcB[1] + kbase, dbp + 4096);
  };

  const int T = K >> 6;  // K-tiles of 64
  stage_half(0, 0);
  stage_half(0, 1);
  PIPE_BAR(4);  // t0-k0 landed (t0-k1 still in flight)

  for (int tile = 0; tile < T; ++tile) {
    const bool stg = (tile + 1 < T);
#pragma unroll
    for (int kk = 0; kk < 2; ++kk) {
      const int reg = ((tile & 1) * 2 + kk) * 8192;
      bf16x8 a[8], b[4];
#pragma unroll
      for (int m = 0; m < 8; ++m) a[m] = *(const bf16x8*)&As[reg + roffA[m]];
#pragma unroll
      for (int n = 0; n < 4; ++n) b[n] = *(const bf16x8*)&Bs[reg + roffB[n]];
      if (stg) stage_half(tile + 1, kk);
      __builtin_amdgcn_s_setprio(1);
#pragma unroll
      for (int m = 0; m < 8; ++m)
#pragma unroll
        for (int n = 0; n < 4; ++n)
          acc[m][n] = __builtin_amdgcn_mfma_f32_16x16x32_bf16(a[m], b[n], acc[m][n], 0, 0, 0);
      __builtin_amdgcn_s_setprio(0);
      if (stg) { PIPE_BAR(4); } else { PIPE_BAR(0); }
    }
  }

  // ---- fused logits (L1/L2): wave's 64 cols belong to one head
  const int colw = bn + wn * 64;
  if (LOGITS && colw < HC) {
    const int head = colw >> 8;
    float as[4], ad[4];
#pragma unroll
    for (int n = 0; n < 4; ++n) {
      int c = (colw + n * 16 + lr) & 255;
      as[n] = a_src[head * 256 + c];
      ad[n] = a_dst[head * 256 + c];
    }
#pragma unroll
    for (int m = 0; m < 8; ++m) {
#pragma unroll
      for (int j = 0; j < 4; ++j) {
        float sp = 0.f, dp = 0.f;
#pragma unroll
        for (int n = 0; n < 4; ++n) { sp += acc[m][n][j] * as[n]; dp += acc[m][n][j] * ad[n]; }
#pragma unroll
        for (int off = 1; off <= 8; off <<= 1) {
          sp += __shfl_xor(sp, off);
          dp += __shfl_xor(dp, off);
        }
        if (lr == 0) {
          int row = bm + wm * 128 + m * 16 + s4 * 4 + j;
          if (row < M) {
            atomicAdd(&sb[row * 4 + head], sp);
            atomicAdd(&db[row * 4 + head], dp);
          }
        }
      }
    }
  }

  // ---- stores: C/D layout col = lane&15, row = (lane>>4)*4 + j
#pragma unroll
  for (int n = 0; n < 4; ++n) {
    int col = bn + wn * 64 + n * 16 + lr;
    if (col >= HC + SC) continue;
    const bool is_h = col < HC;
    float bv = is_h ? 0.f : skip_bias[col - HC];
#pragma unroll
    for (int m = 0; m < 8; ++m) {
#pragma unroll
      for (int j = 0; j < 4; ++j) {
        int row = bm + wm * 128 + m * 16 + s4 * 4 + j;
        if (row >= M) continue;
        float v = acc[m][n][j] + bv;
        if (is_h) {
          h_out[(size_t)row * HC + col] = f2bf(v);
        } else if (SKIP_BF16) {
          ((ushort_t*)skip_out)[(size_t)row * SC + (col - HC)] = f2bf(v);
        } else {
          ((float*)skip_out)[(size_t)row * SC + (col - HC)] = v;
        }
      }
    }
  }
}

// ---------------------------------------------------------------- 128x128 ring GEMM (kept for L3)
template<int NCT, int HC, int SC, bool LOGITS, bool SKIP_BF16, bool SD_COLS>
__global__ __launch_bounds__(256) void gemm_fused(const ushort_t* __restrict__ A,
                                                  const ushort_t* __restrict__ BT,
                                                  const float* __restrict__ skip_bias,
                                                  const float* __restrict__ a_src,
                                                  const float* __restrict__ a_dst,
                                                  float* __restrict__ sb,
                                                  float* __restrict__ db,
                                                  ushort_t* __restrict__ h_out,
                                                  void* __restrict__ skip_out,
                                                  int M, int K) {
  __shared__ ushort_t As[4][128 * 32];
  __shared__ ushort_t Bs[4][128 * 32];
  const int gx = gridDim.x;
  const int nwg = gx * (int)gridDim.y;
  const int orig = blockIdx.y * gx + blockIdx.x;
  const int q = nwg >> 3, r = nwg & 7, xcd = orig & 7;
  const int wgid = (xcd < r ? xcd * (q + 1) : r * (q + 1) + (xcd - r) * q) + (orig >> 3);
  const int bm = (wgid / gx) * 128, bn = (wgid % gx) * 128;

  const int t = threadIdx.x;
  const int l = t & 63, wid = t >> 6;
  const int wm = wid >> 1, wn = wid & 1;

  size_t goffA[2], goffB[2];
  for (int i = 0; i < 2; ++i) {
    int seg = wid * 2 + i;
    int row = seg * 16 + (l >> 2);
    int p = l & 3;
    int ls = p ^ ((row >> 1) & 3);
    int ga = min(bm + row, M - 1);
    int gb = min(bn + row, NCT - 1);
    goffA[i] = (size_t)ga * K + ls * 8;
    goffB[i] = (size_t)gb * K + ls * 8;
  }

  const int lr = l & 15, s = l >> 4;
  int raddrA[4], raddrB[4];
  for (int m = 0; m < 4; ++m) {
    int rowA = wm * 64 + m * 16 + lr;
    raddrA[m] = rowA * 32 + (s ^ ((rowA >> 1) & 3)) * 8;
    int rowB = wn * 64 + m * 16 + lr;
    raddrB[m] = rowB * 32 + (s ^ ((rowB >> 1) & 3)) * 8;
  }

  f32x4 acc[4][4] = {};
  auto stage = [&](int st) {
    int buf = st & 3;
    int k0 = st * 32;
    gload_lds16(A + goffA[0] + k0, &As[buf][(wid * 2 + 0) * 512]);
    gload_lds16(A + goffA[1] + k0, &As[buf][(wid * 2 + 1) * 512]);
    gload_lds16(BT + goffB[0] + k0, &Bs[buf][(wid * 2 + 0) * 512]);
    gload_lds16(BT + goffB[1] + k0, &Bs[buf][(wid * 2 + 1) * 512]);
  };
  auto body = [&](int st) {
    int buf = st & 3;
    bf16x8 a[4], b[4];
#pragma unroll
    for (int m = 0; m < 4; ++m) a[m] = *(const bf16x8*)&As[buf][raddrA[m]];
#pragma unroll
    for (int n = 0; n < 4; ++n) b[n] = *(const bf16x8*)&Bs[buf][raddrB[n]];
#pragma unroll
    for (int m = 0; m < 4; ++m)
#pragma unroll
      for (int n = 0; n < 4; ++n)
        acc[m][n] = __builtin_amdgcn_mfma_f32_16x16x32_bf16(a[m], b[n], acc[m][n], 0, 0, 0);
  };

  const int T = K >> 5;
  stage(0); stage(1); stage(2);
  int st = 0;
  for (; st < T - 3; ++st) {
    PIPE_BAR(8);
    body(st);
    stage(st + 3);
  }
  PIPE_BAR(8); body(T - 3);
  PIPE_BAR(4); body(T - 2);
  PIPE_BAR(0); body(T - 1);

  const int colw = bn + wn * 64;
  if (LOGITS && colw < HC) {
    const int head = colw >> 8;
    float as[4], ad[4];
#pragma unroll
    for (int n = 0; n < 4; ++n) {
      int c = (colw + n * 16 + lr) & 255;
      as[n] = a_src[head * 256 + c];
      ad[n] = a_dst[head * 256 + c];
    }
#pragma unroll
    for (int m = 0; m < 4; ++m) {
#pragma unroll
      for (int j = 0; j < 4; ++j) {
        float sp = 0.f, dp = 0.f;
#pragma unroll
        for (int n = 0; n < 4; ++n) { sp += acc[m][n][j] * as[n]; dp += acc[m][n][j] * ad[n]; }
#pragma unroll
        for (int off = 1; off <= 8; off <<= 1) {
          sp += __shfl_xor(sp, off);
          dp += __shfl_xor(dp, off);
        }
        if (lr == 0) {
          int row = bm + wm * 64 + m * 16 + (l >> 4) * 4 + j;
          if (row < M) {
            atomicAdd(&sb[row * 4 + head], sp);
            atomicAdd(&db[row * 4 + head], dp);
          }
        }
      }
    }
  }

#pragma unroll
  for (int n = 0; n < 4; ++n) {
    int col = bn + wn * 64 + n * 16 + lr;
    if (col >= HC + SC + (SD_COLS ? 12 : 0)) continue;
    const bool is_h = col < HC;
    const bool is_skip = !is_h && col < HC + SC;
    float bv = is_skip ? skip_bias[col - HC] : 0.f;
#pragma unroll
    for (int m = 0; m < 4; ++m) {
#pragma unroll
      for (int j = 0; j < 4; ++j) {
        int row = bm + wm * 64 + m * 16 + (l >> 4) * 4 + j;
        if (row >= M) continue;
        float v = acc[m][n][j] + bv;
        if (is_h) {
          h_out[(size_t)row * HC + col] = f2bf(v);
        } else if (is_skip) {
          if (SKIP_BF16) ((ushort_t*)skip_out)[(size_t)row * SC + (col - HC)] = f2bf(v);
          else           ((float*)skip_out)[(size_t)row * SC + (col - HC)] = v;
        } else if (SD_COLS) {
          int jj = col - (HC + SC);
          if (jj < 6) sb[row * 6 + jj] = v;
          else        db[row * 6 + (jj - 6)] = v;
        }
      }
    }
  }
}

// ---------------------------------------------------------------- attention + aggregate
template<int H, int C, bool ELU_OUT, bool MEAN_HEADS>
__global__ __launch_bounds__(256) void attn_k(const ushort_t* __restrict__ hfeat,
                                              const float* __restrict__ sbuf,
                                              const float* __restrict__ dbuf,
                                              const int* __restrict__ indptr,
                                              const int* __restrict__ esrc,
                                              const float* __restrict__ bias,
                                              const void* __restrict__ skip_v,
                                              void* __restrict__ out_v) {
  constexpr int F = H * C;
  constexpr int CPT = (F + 255) / 256;   // 4 (F=1024) or 2 (F=384)
  constexpr int CH = 256 / H;            // edge chunk: 64 (H=4), 42 (H=6)
  __shared__ float m_l[H], invden_l[H], d_l[H];
  __shared__ float alpha_l[CH * H];
  __shared__ int src_l[CH];
  __shared__ float accs[MEAN_HEADS ? F : 4];

  const int node = blockIdx.x;
  const int t = threadIdx.x;
  const int beg = indptr[node];
  const int deg = indptr[node + 1] - beg;
  if (t < H) d_l[t] = dbuf[node * H + t];
  __syncthreads();

  const int wave = t >> 6, lane = t & 63;
  for (int hd = wave; hd < H; hd += 4) {
    const float dn = d_l[hd];
    float mx = -1e30f;
    for (int i = lane; i < deg; i += 64) {
      int se = esrc[beg + i];
      float e = sbuf[se * H + hd] + dn;
      e = fmaxf(e, 0.2f * e);  // leaky relu
      mx = fmaxf(mx, e);
    }
    for (int off = 32; off; off >>= 1) mx = fmaxf(mx, __shfl_xor(mx, off));
    float den = 0.f;
    for (int i = lane; i < deg; i += 64) {
      int se = esrc[beg + i];
      float e = sbuf[se * H + hd] + dn;
      e = fmaxf(e, 0.2f * e);
      den += __expf(e - mx);
    }
    for (int off = 32; off; off >>= 1) den += __shfl_xor(den, off);
    if (lane == 0) { m_l[hd] = mx; invden_l[hd] = 1.f / den; }
  }
  __syncthreads();

  float acc[CPT] = {};
  const int c0 = t * CPT;
  const int myhead = c0 / C;
  for (int cb = 0; cb < deg; cb += CH) {
    const int ce = min(CH, deg - cb);
    if (t < ce * H) {
      int e_i = t / H, hd = t % H;
      int se = esrc[beg + cb + e_i];
      if (hd == 0) src_l[e_i] = se;
      float e = sbuf[se * H + hd] + d_l[hd];
      e = fmaxf(e, 0.2f * e);
      alpha_l[e_i * H + hd] = __expf(e - m_l[hd]) * invden_l[hd];
    }
    __syncthreads();
    if (c0 < F) {
      for (int e_i = 0; e_i < ce; ++e_i) {
        int se = src_l[e_i];
        float al = alpha_l[e_i * H + myhead];
        const ushort_t* hp = hfeat + (size_t)se * F + c0;
        if (CPT == 4) {
          ushort4 v = *(const ushort4*)hp;
          acc[0] += al * bf2f(v.x); acc[1] += al * bf2f(v.y);
          acc[2] += al * bf2f(v.z); acc[3] += al * bf2f(v.w);
        } else {
          ushort2 v = *(const ushort2*)hp;
          acc[0] += al * bf2f(v.x); acc[1] += al * bf2f(v.y);
        }
      }
    }
    __syncthreads();
  }

  if (!MEAN_HEADS) {
    if (c0 < F) {
      const ushort_t* skip = (const ushort_t*)skip_v;
      ushort_t* out = (ushort_t*)out_v;
      ushort4 sv = *(const ushort4*)&skip[(size_t)node * F + c0];
      float sk[4] = {bf2f(sv.x), bf2f(sv.y), bf2f(sv.z), bf2f(sv.w)};
      ushort_t r[CPT];
#pragma unroll
      for (int j = 0; j < CPT; ++j) {
        float x = acc[j] + bias[c0 + j] + sk[j];
        if (ELU_OUT) x = x > 0.f ? x : __expf(x) - 1.f;
        r[j] = f2bf(x);
      }
      ushort4 o; o.x = r[0]; o.y = r[1]; o.z = r[2]; o.w = r[3];
      *(ushort4*)&out[(size_t)node * F + c0] = o;
    }
  } else {
    const float* skip = (const float*)skip_v;
    float* out = (float*)out_v;
    if (c0 < F) { accs[c0] = acc[0]; accs[c0 + 1] = acc[1]; }
    __syncthreads();
    if (t < C) {
      float sum = 0.f;
#pragma unroll
      for (int hd = 0; hd < H; ++hd) sum += accs[hd * C + t];
      out[(size_t)node * C + t] = sum * (1.f / (float)H) + bias[t] + skip[(size_t)node * C + t];
    }
  }
}

// ---------------------------------------------------------------- launch
extern "C" void kernel_launch(void* const* d_in, const int* in_sizes, int n_in,
                              void* d_out, int out_size, void* d_ws, size_t ws_size,
                              hipStream_t stream) {
  const float* x      = (const float*)d_in[0];
  const int*   ei     = (const int*)d_in[1];
  const float* W1     = (const float*)d_in[2];
  const float* a1s    = (const float*)d_in[3];
  const float* a1d    = (const float*)d_in[4];
  const float* b1     = (const float*)d_in[5];
  const float* lin1W  = (const float*)d_in[6];
  const float* lin1b  = (const float*)d_in[7];
  const float* W2     = (const float*)d_in[8];
  const float* a2s    = (const float*)d_in[9];
  const float* a2d    = (const float*)d_in[10];
  const float* b2     = (const float*)d_in[11];
  const float* lin2W  = (const float*)d_in[12];
  const float* lin2b  = (const float*)d_in[13];
  const float* W3     = (const float*)d_in[14];
  const float* a3s    = (const float*)d_in[15];
  const float* a3d    = (const float*)d_in[16];
  const float* b3     = (const float*)d_in[17];
  const float* lin3W  = (const float*)d_in[18];
  const float* lin3b  = (const float*)d_in[19];

  const int N = in_sizes[0] / 128;
  const int E = in_sizes[1] / 2;
  const int* src = ei;
  const int* dst = ei + E;

  char* ws = (char*)d_ws;
  size_t off = 0;
  auto alloc = [&](size_t bytes) -> void* {
    void* p = ws + off;
    off += (bytes + 255) & ~(size_t)255;
    return p;
  };
  ushort_t* h_bf    = (ushort_t*)alloc((size_t)N * 1024 * 2);
  ushort_t* skip_bf = (ushort_t*)alloc((size_t)N * 1024 * 2);
  float*    skip3   = (float*)alloc((size_t)N * 64 * 4);
  ushort_t* act_bf  = (ushort_t*)alloc((size_t)N * 1024 * 2);
  ushort_t* x_bf    = (ushort_t*)alloc((size_t)N * 128 * 2);
  ushort_t* W1cat   = (ushort_t*)alloc((size_t)2048 * 128 * 2);
  ushort_t* W2cat   = (ushort_t*)alloc((size_t)2048 * 1024 * 2);
  ushort_t* W3cat   = (ushort_t*)alloc((size_t)512 * 1024 * 2);  // 448..459 folded a3, 460+ zero
  float*    sd12    = (float*)alloc((size_t)4 * N * 4 * 4);      // sb1,db1,sb2,db2 contiguous
  float*    sb1 = sd12, *db1 = sd12 + N * 4, *sb2 = sd12 + 2 * N * 4, *db2 = sd12 + 3 * N * 4;
  float*    sb3     = (float*)alloc((size_t)N * 6 * 4);
  float*    db3     = (float*)alloc((size_t)N * 6 * 4);
  int*      indptr  = (int*)alloc((size_t)(N + 1) * 4);
  int*      cursor  = (int*)alloc((size_t)N * 4);
  int*      esrc    = (int*)alloc((size_t)(E + N) * 4);

  const int NZ = 4 * N * 4;
  init_k<<<(max(N, NZ) + 255) / 256, 256, 0, stream>>>(cursor, N, sd12, NZ);
  count_edges_k<<<(E + 255) / 256, 256, 0, stream>>>(dst, E, cursor);
  scan_k<<<1, 1024, 0, stream>>>(cursor, indptr, cursor, N);
  scatter_k<<<(E + N + 255) / 256, 256, 0, stream>>>(src, dst, E, N, cursor, esrc);

  cast_bf16_k<<<(N * 128 / 4 + 255) / 256, 256, 0, stream>>>(x, x_bf, N * 128 / 4);
  transpose_dual_k<<<dim3(64, 4), 256, 0, stream>>>(W1, 1024, lin1W, 1024, 128, W1cat);
  transpose_dual_k<<<dim3(64, 32), 256, 0, stream>>>(W2, 1024, lin2W, 1024, 1024, W2cat);
  transpose_dual_k<<<dim3(14, 32), 256, 0, stream>>>(W3, 384, lin3W, 64, 1024, W3cat);
  fold_a3_k<<<4, 256, 0, stream>>>(W3, a3s, a3d, W3cat);

  const int MB  = (N + 127) / 128;
  const int MB2 = (N + 255) / 256;
  // ---- Layer 1 (K=128): 256x256 phase-split GEMM + fused logits
  gemm256<2048, 1024, 1024, true, true><<<dim3(8, MB2), 512, 0, stream>>>(
      x_bf, W1cat, lin1b, a1s, a1d, sb1, db1, h_bf, skip_bf, N, 128);
  attn_k<4, 256, true, false><<<N, 256, 0, stream>>>(h_bf, sb1, db1, indptr, esrc, b1, skip_bf, act_bf);
  // ---- Layer 2 (K=1024)
  gemm256<2048, 1024, 1024, true, true><<<dim3(8, MB2), 512, 0, stream>>>(
      act_bf, W2cat, lin2b, a2s, a2d, sb2, db2, h_bf, skip_bf, N, 1024);
  attn_k<4, 256, true, false><<<N, 256, 0, stream>>>(h_bf, sb2, db2, indptr, esrc, b2, skip_bf, act_bf);
  // ---- Layer 3 (128x128 ring; logits via folded cols 448..459)
  gemm_fused<512, 384, 64, false, false, true><<<dim3(4, MB), 256, 0, stream>>>(
      act_bf, W3cat, lin3b, nullptr, nullptr, sb3, db3, h_bf, skip3, N, 1024);
  attn_k<6, 64, false, true><<<N, 256, 0, stream>>>(h_bf, sb3, db3, indptr, esrc, b3, skip3, d_out);
}

// Round 8
// 390.467 us; speedup vs baseline: 1.1291x; 1.1291x over previous
//
#include <hip/hip_runtime.h>
#include <math.h>

typedef unsigned short ushort_t;
typedef __attribute__((ext_vector_type(8))) short bf16x8;
typedef __attribute__((ext_vector_type(4))) float f32x4;

__device__ __forceinline__ ushort_t f2bf(float f) {
  unsigned u = __float_as_uint(f);
  unsigned r = (u + 0x7FFF + ((u >> 16) & 1)) >> 16;  // RNE
  return (ushort_t)r;
}
__device__ __forceinline__ float bf2f(ushort_t u) {
  return __uint_as_float(((unsigned)u) << 16);
}

__device__ __forceinline__ void gload_lds16(const void* g, void* l) {
  __builtin_amdgcn_global_load_lds(
      (const __attribute__((address_space(1))) void*)g,
      (__attribute__((address_space(3))) void*)l, 16, 0, 0);
}

#define PIPE_BAR(N)                                          \
  do {                                                       \
    asm volatile("s_waitcnt vmcnt(" #N ")" ::: "memory");    \
    __builtin_amdgcn_s_barrier();                            \
    asm volatile("" ::: "memory");                           \
  } while (0)

// ---------------------------------------------------------------- CSR
__global__ void init_k(int* __restrict__ cursor, int n, float* __restrict__ z, int nz) {
  int i = blockIdx.x * blockDim.x + threadIdx.x;
  if (i < n) cursor[i] = 1;  // self-loop
  if (i < nz) z[i] = 0.f;
}

__global__ void count_edges_k(const int* __restrict__ dst, int E, int* __restrict__ cnt) {
  int i = blockIdx.x * blockDim.x + threadIdx.x;
  if (i < E) atomicAdd(&cnt[dst[i]], 1);
}

// exclusive scan via wave shuffles; writes indptr AND cursor
__global__ void scan_k(const int* __restrict__ cnt, int* __restrict__ indptr,
                       int* __restrict__ cursor, int n) {
  __shared__ int wsum[16];
  __shared__ int carry_s;
  const int t = threadIdx.x, lane = t & 63, w = t >> 6;
  if (t == 0) carry_s = 0;
  __syncthreads();
  for (int base = 0; base < n; base += 1024) {
    int i = base + t;
    int v = (i < n) ? cnt[i] : 0;
    int x = v;  // inclusive scan within wave
#pragma unroll
    for (int off = 1; off < 64; off <<= 1) {
      int y = __shfl_up(x, off);
      if (lane >= off) x += y;
    }
    if (lane == 63) wsum[w] = x;
    __syncthreads();
    if (w == 0 && lane < 16) {
      int y = wsum[lane];
#pragma unroll
      for (int off = 1; off < 16; off <<= 1) {
        int z = __shfl_up(y, off);
        if (lane >= off) y += z;
      }
      wsum[lane] = y;
    }
    __syncthreads();
    int woff = (w == 0) ? 0 : wsum[w - 1];
    int carry = carry_s;
    int incl = x + woff + carry;
    if (i < n) { indptr[i] = incl - v; cursor[i] = incl - v; }
    __syncthreads();
    if (t == 1023) carry_s = incl;
    __syncthreads();
  }
  if (threadIdx.x == 0) indptr[n] = carry_s;
}

__global__ void scatter_k(const int* __restrict__ src, const int* __restrict__ dst, int E, int n,
                          int* __restrict__ cursor, int* __restrict__ esrc) {
  int i = blockIdx.x * blockDim.x + threadIdx.x;
  if (i < E) {
    int p = atomicAdd(&cursor[dst[i]], 1);
    esrc[p] = src[i];
  } else if (i < E + n) {
    int node = i - E;
    int p = atomicAdd(&cursor[node], 1);
    esrc[p] = node;
  }
}

// ---------------------------------------------------------------- merged prep kernel
// blocks [0,1250): cast x->bf16 ; [1250,1506): W1cat ; [1506,3554): W2cat ;
// [3554,4002): W3cat ; [4002,4006): fold a3 into W3cat rows 448..459 (+zero pad).
__device__ void transpose_dual_body(const float* __restrict__ Wa, int Na,
                                    const float* __restrict__ Wb, int Nb,
                                    int K, ushort_t* __restrict__ dst,
                                    int bxi, int byi, float (*tile)[33]) {
  const int bx = bxi * 32, by = byi * 32;
  const int tx = threadIdx.x & 31, ty = threadIdx.x >> 5;
  const bool isB = bx >= Na;
  const float* W = isB ? Wb : Wa;
  const int Nw = isB ? Nb : Na;
  const int nc = bx - (isB ? Na : 0) + tx;
  for (int i = ty; i < 32; i += 8)
    tile[i][tx] = W[(size_t)(by + i) * Nw + nc];
  __syncthreads();
  for (int i = ty; i < 32; i += 8)
    dst[(size_t)(bx + i) * K + by + tx] = f2bf(tile[tx][i]);
}

__global__ __launch_bounds__(256) void prep_k(const float* __restrict__ x, ushort_t* __restrict__ x_bf, int n4,
                                              const float* __restrict__ W1, const float* __restrict__ l1W, ushort_t* __restrict__ W1cat,
                                              const float* __restrict__ W2, const float* __restrict__ l2W, ushort_t* __restrict__ W2cat,
                                              const float* __restrict__ W3, const float* __restrict__ l3W, ushort_t* __restrict__ W3cat,
                                              const float* __restrict__ a3s, const float* __restrict__ a3d) {
  __shared__ float tile[32][33];
  const int b = blockIdx.x, t = threadIdx.x;
  if (b < 1250) {
    int i = b * 256 + t;
    if (i < n4) {
      float4 v = ((const float4*)x)[i];
      ushort_t* p = x_bf + i * 4;
      p[0] = f2bf(v.x); p[1] = f2bf(v.y); p[2] = f2bf(v.z); p[3] = f2bf(v.w);
    }
  } else if (b < 1506) {
    int lo = b - 1250;  // (64,4)
    transpose_dual_body(W1, 1024, l1W, 1024, 128, W1cat, lo % 64, lo / 64, tile);
  } else if (b < 3554) {
    int lo = b - 1506;  // (64,32)
    transpose_dual_body(W2, 1024, l2W, 1024, 1024, W2cat, lo % 64, lo / 64, tile);
  } else if (b < 4002) {
    int lo = b - 3554;  // (14,32)
    transpose_dual_body(W3, 384, l3W, 64, 1024, W3cat, lo % 14, lo / 14, tile);
  } else {
    int k = (b - 4002) * 256 + t;  // 0..1023
    const float* row = W3 + (size_t)k * 384;
    for (int hd = 0; hd < 6; ++hd) {
      float ss = 0.f, dd = 0.f;
      for (int c = 0; c < 64; ++c) {
        float w = row[hd * 64 + c];
        ss += w * a3s[hd * 64 + c];
        dd += w * a3d[hd * 64 + c];
      }
      W3cat[(size_t)(448 + hd) * 1024 + k] = f2bf(ss);
      W3cat[(size_t)(454 + hd) * 1024 + k] = f2bf(dd);
    }
    for (int j = 460; j < 512; ++j) W3cat[(size_t)j * 1024 + k] = 0;
  }
}

// ---------------------------------------------------------------- gemm320: BM=320 BN=256 BK=64
// 8 waves (2M x 4N), per-wave 160x64 = acc[10][4]. Grid = 32x8 = 256 blocks exactly (1 round).
// LDS 144KB: A[2][320][64], B[2][256][64] ushort, k-slot XOR swizzle (slot = ks ^ (row&7)).
// Staging: 9 gload_lds/tile (5 A + 4 B), 64 rows/call (8 rows per wave, linear dest).
// One vmcnt(0)+barrier per K-tile (80 MFMA/barrier).
template<int NCT, int HC, int SC, bool LOGITS>
__global__ __launch_bounds__(512, 2) void gemm320(const ushort_t* __restrict__ A,
                                                  const ushort_t* __restrict__ BT,
                                                  const float* __restrict__ skip_bias,
                                                  const float* __restrict__ a_src,
                                                  const float* __restrict__ a_dst,
                                                  float* __restrict__ sb,
                                                  float* __restrict__ db,
                                                  ushort_t* __restrict__ h_out,
                                                  ushort_t* __restrict__ skip_out,
                                                  int M, int K) {
  __shared__ ushort_t As[2 * 320 * 64];  // 80 KB
  __shared__ ushort_t Bs[2 * 256 * 64];  // 64 KB
  const int gx = gridDim.x;
  const int nwg = gx * (int)gridDim.y;
  const int orig = blockIdx.y * gx + blockIdx.x;
  const int q = nwg >> 3, r = nwg & 7, xcd = orig & 7;
  const int wgid = (xcd < r ? xcd * (q + 1) : r * (q + 1) + (xcd - r) * q) + (orig >> 3);
  const int bm = (wgid / gx) * 320, bn = (wgid % gx) * 256;

  const int t = threadIdx.x, l = t & 63, wid = t >> 6;
  const int wm = wid >> 2, wn = wid & 3;  // 2 x 4
  const int lr = l & 15, s4 = l >> 4;

  const int scall_row = wid * 8 + (l >> 3);     // row within a 64-row staging call
  const int s_src = (l & 7) ^ (l >> 3);         // source k-slot (inverse swizzle)

  auto stage_tile = [&](int tile) {
    const int buf = tile & 1;
    const size_t kcol = (size_t)tile * 64 + s_src * 8;
#pragma unroll
    for (int c = 0; c < 5; ++c) {
      int gr = min(bm + c * 64 + scall_row, M - 1);
      gload_lds16(A + (size_t)gr * K + kcol, &As[(buf * 320 + c * 64 + wid * 8) * 64]);
    }
#pragma unroll
    for (int c = 0; c < 4; ++c) {
      int gr = bn + c * 64 + scall_row;
      gload_lds16(BT + (size_t)gr * K + kcol, &Bs[(buf * 256 + gr - bn - scall_row + scall_row) * 64]);
    }
  };

  f32x4 acc[10][4] = {};

  const int T = K >> 6;
  stage_tile(0);
  PIPE_BAR(0);

  for (int tile = 0; tile < T; ++tile) {
    const int buf = tile & 1;
#pragma unroll
    for (int kk = 0; kk < 2; ++kk) {
      bf16x8 b[4];
#pragma unroll
      for (int n = 0; n < 4; ++n) {
        int rb = wn * 64 + n * 16 + lr;
        b[n] = *(const bf16x8*)&Bs[(buf * 256 + rb) * 64 + (((kk * 4 + s4) ^ (rb & 7)) << 3)];
      }
      bf16x8 a[5];
#pragma unroll
      for (int m = 0; m < 5; ++m) {
        int ra = wm * 160 + m * 16 + lr;
        a[m] = *(const bf16x8*)&As[(buf * 320 + ra) * 64 + (((kk * 4 + s4) ^ (ra & 7)) << 3)];
      }
      if (kk == 0 && tile + 1 < T) stage_tile(tile + 1);
      __builtin_amdgcn_s_setprio(1);
#pragma unroll
      for (int m = 0; m < 5; ++m)
#pragma unroll
        for (int n = 0; n < 4; ++n)
          acc[m][n] = __builtin_amdgcn_mfma_f32_16x16x32_bf16(a[m], b[n], acc[m][n], 0, 0, 0);
      __builtin_amdgcn_s_setprio(0);
#pragma unroll
      for (int m = 0; m < 5; ++m) {
        int ra = wm * 160 + (m + 5) * 16 + lr;
        a[m] = *(const bf16x8*)&As[(buf * 320 + ra) * 64 + (((kk * 4 + s4) ^ (ra & 7)) << 3)];
      }
      __builtin_amdgcn_s_setprio(1);
#pragma unroll
      for (int m = 0; m < 5; ++m)
#pragma unroll
        for (int n = 0; n < 4; ++n)
          acc[m + 5][n] = __builtin_amdgcn_mfma_f32_16x16x32_bf16(a[m], b[n], acc[m + 5][n], 0, 0, 0);
      __builtin_amdgcn_s_setprio(0);
      __builtin_amdgcn_sched_barrier(0);
    }
    if (tile + 1 < T) { PIPE_BAR(0); }
  }

  // ---- fused logits (L1/L2): wave's 64 cols belong to one head
  const int colw = bn + wn * 64;
  if (LOGITS && colw < HC) {
    const int head = colw >> 8;
    float as[4], ad[4];
#pragma unroll
    for (int n = 0; n < 4; ++n) {
      int c = (colw + n * 16 + lr) & 255;
      as[n] = a_src[head * 256 + c];
      ad[n] = a_dst[head * 256 + c];
    }
#pragma unroll
    for (int m = 0; m < 10; ++m) {
#pragma unroll
      for (int j = 0; j < 4; ++j) {
        float sp = 0.f, dp = 0.f;
#pragma unroll
        for (int n = 0; n < 4; ++n) { sp += acc[m][n][j] * as[n]; dp += acc[m][n][j] * ad[n]; }
#pragma unroll
        for (int off = 1; off <= 8; off <<= 1) {
          sp += __shfl_xor(sp, off);
          dp += __shfl_xor(dp, off);
        }
        if (lr == 0) {
          int row = bm + wm * 160 + m * 16 + s4 * 4 + j;
          if (row < M) {
            atomicAdd(&sb[row * 4 + head], sp);
            atomicAdd(&db[row * 4 + head], dp);
          }
        }
      }
    }
  }

  // ---- stores: C/D layout col = lane&15, row = (lane>>4)*4 + j
#pragma unroll
  for (int n = 0; n < 4; ++n) {
    int col = bn + wn * 64 + n * 16 + lr;
    if (col >= HC + SC) continue;
    const bool is_h = col < HC;
    float bv = is_h ? 0.f : skip_bias[col - HC];
#pragma unroll
    for (int m = 0; m < 10; ++m) {
#pragma unroll
      for (int j = 0; j < 4; ++j) {
        int row = bm + wm * 160 + m * 16 + s4 * 4 + j;
        if (row >= M) continue;
        float v = acc[m][n][j] + bv;
        if (is_h) h_out[(size_t)row * HC + col] = f2bf(v);
        else      skip_out[(size_t)row * SC + (col - HC)] = f2bf(v);
      }
    }
  }
}

// ---------------------------------------------------------------- 128x128 ring GEMM (L3)
template<int NCT, int HC, int SC, bool SD_COLS>
__global__ __launch_bounds__(256) void gemm_fused(const ushort_t* __restrict__ A,
                                                  const ushort_t* __restrict__ BT,
                                                  const float* __restrict__ skip_bias,
                                                  float* __restrict__ sb,
                                                  float* __restrict__ db,
                                                  ushort_t* __restrict__ h_out,
                                                  float* __restrict__ skip_out,
                                                  int M, int K) {
  __shared__ ushort_t As[4][128 * 32];
  __shared__ ushort_t Bs[4][128 * 32];
  const int gx = gridDim.x;
  const int nwg = gx * (int)gridDim.y;
  const int orig = blockIdx.y * gx + blockIdx.x;
  const int q = nwg >> 3, r = nwg & 7, xcd = orig & 7;
  const int wgid = (xcd < r ? xcd * (q + 1) : r * (q + 1) + (xcd - r) * q) + (orig >> 3);
  const int bm = (wgid / gx) * 128, bn = (wgid % gx) * 128;

  const int t = threadIdx.x;
  const int l = t & 63, wid = t >> 6;
  const int wm = wid >> 1, wn = wid & 1;

  size_t goffA[2], goffB[2];
  for (int i = 0; i < 2; ++i) {
    int seg = wid * 2 + i;
    int row = seg * 16 + (l >> 2);
    int p = l & 3;
    int ls = p ^ ((row >> 1) & 3);
    int ga = min(bm + row, M - 1);
    int gb = min(bn + row, NCT - 1);
    goffA[i] = (size_t)ga * K + ls * 8;
    goffB[i] = (size_t)gb * K + ls * 8;
  }

  const int lr = l & 15, s = l >> 4;
  int raddrA[4], raddrB[4];
  for (int m = 0; m < 4; ++m) {
    int rowA = wm * 64 + m * 16 + lr;
    raddrA[m] = rowA * 32 + (s ^ ((rowA >> 1) & 3)) * 8;
    int rowB = wn * 64 + m * 16 + lr;
    raddrB[m] = rowB * 32 + (s ^ ((rowB >> 1) & 3)) * 8;
  }

  f32x4 acc[4][4] = {};
  auto stage = [&](int st) {
    int buf = st & 3;
    int k0 = st * 32;
    gload_lds16(A + goffA[0] + k0, &As[buf][(wid * 2 + 0) * 512]);
    gload_lds16(A + goffA[1] + k0, &As[buf][(wid * 2 + 1) * 512]);
    gload_lds16(BT + goffB[0] + k0, &Bs[buf][(wid * 2 + 0) * 512]);
    gload_lds16(BT + goffB[1] + k0, &Bs[buf][(wid * 2 + 1) * 512]);
  };
  auto body = [&](int st) {
    int buf = st & 3;
    bf16x8 a[4], b[4];
#pragma unroll
    for (int m = 0; m < 4; ++m) a[m] = *(const bf16x8*)&As[buf][raddrA[m]];
#pragma unroll
    for (int n = 0; n < 4; ++n) b[n] = *(const bf16x8*)&Bs[buf][raddrB[n]];
#pragma unroll
    for (int m = 0; m < 4; ++m)
#pragma unroll
      for (int n = 0; n < 4; ++n)
        acc[m][n] = __builtin_amdgcn_mfma_f32_16x16x32_bf16(a[m], b[n], acc[m][n], 0, 0, 0);
  };

  const int T = K >> 5;
  stage(0); stage(1); stage(2);
  int st = 0;
  for (; st < T - 3; ++st) {
    PIPE_BAR(8);
    body(st);
    stage(st + 3);
  }
  PIPE_BAR(8); body(T - 3);
  PIPE_BAR(4); body(T - 2);
  PIPE_BAR(0); body(T - 1);

#pragma unroll
  for (int n = 0; n < 4; ++n) {
    int col = bn + wn * 64 + n * 16 + lr;
    if (col >= HC + SC + (SD_COLS ? 12 : 0)) continue;
    const bool is_h = col < HC;
    const bool is_skip = !is_h && col < HC + SC;
    float bv = is_skip ? skip_bias[col - HC] : 0.f;
#pragma unroll
    for (int m = 0; m < 4; ++m) {
#pragma unroll
      for (int j = 0; j < 4; ++j) {
        int row = bm + wm * 64 + m * 16 + (l >> 4) * 4 + j;
        if (row >= M) continue;
        float v = acc[m][n][j] + bv;
        if (is_h) {
          h_out[(size_t)row * HC + col] = f2bf(v);
        } else if (is_skip) {
          skip_out[(size_t)row * SC + (col - HC)] = v;
        } else if (SD_COLS) {
          int jj = col - (HC + SC);
          if (jj < 6) sb[row * 6 + jj] = v;
          else        db[row * 6 + (jj - 6)] = v;
        }
      }
    }
  }
}

// ---------------------------------------------------------------- attention + aggregate
template<int H, int C, bool ELU_OUT, bool MEAN_HEADS>
__global__ __launch_bounds__(256) void attn_k(const ushort_t* __restrict__ hfeat,
                                              const float* __restrict__ sbuf,
                                              const float* __restrict__ dbuf,
                                              const int* __restrict__ indptr,
                                              const int* __restrict__ esrc,
                                              const float* __restrict__ bias,
                                              const void* __restrict__ skip_v,
                                              void* __restrict__ out_v) {
  constexpr int F = H * C;
  constexpr int CPT = (F + 255) / 256;
  constexpr int CH = 256 / H;
  __shared__ float m_l[H], invden_l[H], d_l[H];
  __shared__ float alpha_l[CH * H];
  __shared__ int src_l[CH];
  __shared__ float accs[MEAN_HEADS ? F : 4];

  const int node = blockIdx.x;
  const int t = threadIdx.x;
  const int beg = indptr[node];
  const int deg = indptr[node + 1] - beg;
  if (t < H) d_l[t] = dbuf[node * H + t];
  __syncthreads();

  const int wave = t >> 6, lane = t & 63;
  for (int hd = wave; hd < H; hd += 4) {
    const float dn = d_l[hd];
    float mx = -1e30f;
    for (int i = lane; i < deg; i += 64) {
      int se = esrc[beg + i];
      float e = sbuf[se * H + hd] + dn;
      e = fmaxf(e, 0.2f * e);
      mx = fmaxf(mx, e);
    }
    for (int off = 32; off; off >>= 1) mx = fmaxf(mx, __shfl_xor(mx, off));
    float den = 0.f;
    for (int i = lane; i < deg; i += 64) {
      int se = esrc[beg + i];
      float e = sbuf[se * H + hd] + dn;
      e = fmaxf(e, 0.2f * e);
      den += __expf(e - mx);
    }
    for (int off = 32; off; off >>= 1) den += __shfl_xor(den, off);
    if (lane == 0) { m_l[hd] = mx; invden_l[hd] = 1.f / den; }
  }
  __syncthreads();

  float acc[CPT] = {};
  const int c0 = t * CPT;
  const int myhead = c0 / C;
  for (int cb = 0; cb < deg; cb += CH) {
    const int ce = min(CH, deg - cb);
    if (t < ce * H) {
      int e_i = t / H, hd = t % H;
      int se = esrc[beg + cb + e_i];
      if (hd == 0) src_l[e_i] = se;
      float e = sbuf[se * H + hd] + d_l[hd];
      e = fmaxf(e, 0.2f * e);
      alpha_l[e_i * H + hd] = __expf(e - m_l[hd]) * invden_l[hd];
    }
    __syncthreads();
    if (c0 < F) {
      for (int e_i = 0; e_i < ce; ++e_i) {
        int se = src_l[e_i];
        float al = alpha_l[e_i * H + myhead];
        const ushort_t* hp = hfeat + (size_t)se * F + c0;
        if (CPT == 4) {
          ushort4 v = *(const ushort4*)hp;
          acc[0] += al * bf2f(v.x); acc[1] += al * bf2f(v.y);
          acc[2] += al * bf2f(v.z); acc[3] += al * bf2f(v.w);
        } else {
          ushort2 v = *(const ushort2*)hp;
          acc[0] += al * bf2f(v.x); acc[1] += al * bf2f(v.y);
        }
      }
    }
    __syncthreads();
  }

  if (!MEAN_HEADS) {
    if (c0 < F) {
      const ushort_t* skip = (const ushort_t*)skip_v;
      ushort_t* out = (ushort_t*)out_v;
      ushort4 sv = *(const ushort4*)&skip[(size_t)node * F + c0];
      float sk[4] = {bf2f(sv.x), bf2f(sv.y), bf2f(sv.z), bf2f(sv.w)};
      ushort_t rr[CPT];
#pragma unroll
      for (int j = 0; j < CPT; ++j) {
        float xo = acc[j] + bias[c0 + j] + sk[j];
        if (ELU_OUT) xo = xo > 0.f ? xo : __expf(xo) - 1.f;
        rr[j] = f2bf(xo);
      }
      ushort4 o; o.x = rr[0]; o.y = rr[1]; o.z = rr[2]; o.w = rr[3];
      *(ushort4*)&out[(size_t)node * F + c0] = o;
    }
  } else {
    const float* skip = (const float*)skip_v;
    float* out = (float*)out_v;
    if (c0 < F) { accs[c0] = acc[0]; accs[c0 + 1] = acc[1]; }
    __syncthreads();
    if (t < C) {
      float sum = 0.f;
#pragma unroll
      for (int hd = 0; hd < H; ++hd) sum += accs[hd * C + t];
      out[(size_t)node * C + t] = sum * (1.f / (float)H) + bias[t] + skip[(size_t)node * C + t];
    }
  }
}

// ---------------------------------------------------------------- launch
extern "C" void kernel_launch(void* const* d_in, const int* in_sizes, int n_in,
                              void* d_out, int out_size, void* d_ws, size_t ws_size,
                              hipStream_t stream) {
  const float* x      = (const float*)d_in[0];
  const int*   ei     = (const int*)d_in[1];
  const float* W1     = (const float*)d_in[2];
  const float* a1s    = (const float*)d_in[3];
  const float* a1d    = (const float*)d_in[4];
  const float* b1     = (const float*)d_in[5];
  const float* lin1W  = (const float*)d_in[6];
  const float* lin1b  = (const float*)d_in[7];
  const float* W2     = (const float*)d_in[8];
  const float* a2s    = (const float*)d_in[9];
  const float* a2d    = (const float*)d_in[10];
  const float* b2     = (const float*)d_in[11];
  const float* lin2W  = (const float*)d_in[12];
  const float* lin2b  = (const float*)d_in[13];
  const float* W3     = (const float*)d_in[14];
  const float* a3s    = (const float*)d_in[15];
  const float* a3d    = (const float*)d_in[16];
  const float* b3     = (const float*)d_in[17];
  const float* lin3W  = (const float*)d_in[18];
  const float* lin3b  = (const float*)d_in[19];

  const int N = in_sizes[0] / 128;
  const int E = in_sizes[1] / 2;
  const int* src = ei;
  const int* dst = ei + E;

  char* ws = (char*)d_ws;
  size_t off = 0;
  auto alloc = [&](size_t bytes) -> void* {
    void* p = ws + off;
    off += (bytes + 255) & ~(size_t)255;
    return p;
  };
  ushort_t* h_bf    = (ushort_t*)alloc((size_t)N * 1024 * 2);
  ushort_t* skip_bf = (ushort_t*)alloc((size_t)N * 1024 * 2);
  float*    skip3   = (float*)alloc((size_t)N * 64 * 4);
  ushort_t* act_bf  = (ushort_t*)alloc((size_t)N * 1024 * 2);
  ushort_t* x_bf    = (ushort_t*)alloc((size_t)N * 128 * 2);
  ushort_t* W1cat   = (ushort_t*)alloc((size_t)2048 * 128 * 2);
  ushort_t* W2cat   = (ushort_t*)alloc((size_t)2048 * 1024 * 2);
  ushort_t* W3cat   = (ushort_t*)alloc((size_t)512 * 1024 * 2);
  float*    sd12    = (float*)alloc((size_t)4 * N * 4 * 4);
  float*    sb1 = sd12, *db1 = sd12 + N * 4, *sb2 = sd12 + 2 * N * 4, *db2 = sd12 + 3 * N * 4;
  float*    sb3     = (float*)alloc((size_t)N * 6 * 4);
  float*    db3     = (float*)alloc((size_t)N * 6 * 4);
  int*      indptr  = (int*)alloc((size_t)(N + 1) * 4);
  int*      cursor  = (int*)alloc((size_t)N * 4);
  int*      esrc    = (int*)alloc((size_t)(E + N) * 4);

  // ---- prep (cast + transposes + fold), independent of CSR
  const int n4 = N * 128 / 4;
  prep_k<<<4006, 256, 0, stream>>>(x, x_bf, n4, W1, lin1W, W1cat, W2, lin2W, W2cat,
                                   W3, lin3W, W3cat, a3s, a3d);

  // ---- CSR
  const int NZ = 4 * N * 4;
  init_k<<<(max(N, NZ) + 255) / 256, 256, 0, stream>>>(cursor, N, sd12, NZ);
  count_edges_k<<<(E + 255) / 256, 256, 0, stream>>>(dst, E, cursor);
  scan_k<<<1, 1024, 0, stream>>>(cursor, indptr, cursor, N);
  scatter_k<<<(E + N + 255) / 256, 256, 0, stream>>>(src, dst, E, N, cursor, esrc);

  const int MB  = (N + 127) / 128;
  const int MB3 = (N + 319) / 320;
  // ---- Layer 1 (K=128)
  gemm320<2048, 1024, 1024, true><<<dim3(8, MB3), 512, 0, stream>>>(
      x_bf, W1cat, lin1b, a1s, a1d, sb1, db1, h_bf, skip_bf, N, 128);
  attn_k<4, 256, true, false><<<N, 256, 0, stream>>>(h_bf, sb1, db1, indptr, esrc, b1, skip_bf, act_bf);
  // ---- Layer 2 (K=1024)
  gemm320<2048, 1024, 1024, true><<<dim3(8, MB3), 512, 0, stream>>>(
      act_bf, W2cat, lin2b, a2s, a2d, sb2, db2, h_bf, skip_bf, N, 1024);
  attn_k<4, 256, true, false><<<N, 256, 0, stream>>>(h_bf, sb2, db2, indptr, esrc, b2, skip_bf, act_bf);
  // ---- Layer 3 (128x128 ring; logits via folded cols 448..459)
  gemm_fused<512, 384, 64, true><<<dim3(4, MB), 256, 0, stream>>>(
      act_bf, W3cat, lin3b, sb3, db3, h_bf, skip3, N, 1024);
  attn_k<6, 64, false, true><<<N, 256, 0, stream>>>(h_bf, sb3, db3, indptr, esrc, b3, skip3, d_out);
}

// Round 9
// 342.349 us; speedup vs baseline: 1.2878x; 1.1406x over previous
//
#include <hip/hip_runtime.h>
#include <math.h>

typedef unsigned short ushort_t;
typedef __attribute__((ext_vector_type(8))) short bf16x8;
typedef __attribute__((ext_vector_type(4))) float f32x4;

__device__ __forceinline__ ushort_t f2bf(float f) {
  unsigned u = __float_as_uint(f);
  unsigned r = (u + 0x7FFF + ((u >> 16) & 1)) >> 16;  // RNE
  return (ushort_t)r;
}
__device__ __forceinline__ float bf2f(ushort_t u) {
  return __uint_as_float(((unsigned)u) << 16);
}

__device__ __forceinline__ void gload_lds16(const void* g, void* l) {
  __builtin_amdgcn_global_load_lds(
      (const __attribute__((address_space(1))) void*)g,
      (__attribute__((address_space(3))) void*)l, 16, 0, 0);
}

#define PIPE_BAR(N)                                          \
  do {                                                       \
    asm volatile("s_waitcnt vmcnt(" #N ")" ::: "memory");    \
    __builtin_amdgcn_s_barrier();                            \
    asm volatile("" ::: "memory");                           \
  } while (0)

// ---------------------------------------------------------------- CSR
__global__ void init_k(int* __restrict__ cursor, int n, float* __restrict__ z, int nz) {
  int i = blockIdx.x * blockDim.x + threadIdx.x;
  if (i < n) cursor[i] = 1;  // self-loop
  if (i < nz) z[i] = 0.f;
}

__global__ void count_edges_k(const int* __restrict__ dst, int E, int* __restrict__ cnt) {
  int i = blockIdx.x * blockDim.x + threadIdx.x;
  if (i < E) atomicAdd(&cnt[dst[i]], 1);
}

// exclusive scan via wave shuffles; writes indptr AND cursor
__global__ void scan_k(const int* __restrict__ cnt, int* __restrict__ indptr,
                       int* __restrict__ cursor, int n) {
  __shared__ int wsum[16];
  __shared__ int carry_s;
  const int t = threadIdx.x, lane = t & 63, w = t >> 6;
  if (t == 0) carry_s = 0;
  __syncthreads();
  for (int base = 0; base < n; base += 1024) {
    int i = base + t;
    int v = (i < n) ? cnt[i] : 0;
    int x = v;
#pragma unroll
    for (int off = 1; off < 64; off <<= 1) {
      int y = __shfl_up(x, off);
      if (lane >= off) x += y;
    }
    if (lane == 63) wsum[w] = x;
    __syncthreads();
    if (w == 0 && lane < 16) {
      int y = wsum[lane];
#pragma unroll
      for (int off = 1; off < 16; off <<= 1) {
        int z = __shfl_up(y, off);
        if (lane >= off) y += z;
      }
      wsum[lane] = y;
    }
    __syncthreads();
    int woff = (w == 0) ? 0 : wsum[w - 1];
    int carry = carry_s;
    int incl = x + woff + carry;
    if (i < n) { indptr[i] = incl - v; cursor[i] = incl - v; }
    __syncthreads();
    if (t == 1023) carry_s = incl;
    __syncthreads();
  }
  if (threadIdx.x == 0) indptr[n] = carry_s;
}

__global__ void scatter_k(const int* __restrict__ src, const int* __restrict__ dst, int E, int n,
                          int* __restrict__ cursor, int* __restrict__ esrc) {
  int i = blockIdx.x * blockDim.x + threadIdx.x;
  if (i < E) {
    int p = atomicAdd(&cursor[dst[i]], 1);
    esrc[p] = src[i];
  } else if (i < E + n) {
    int node = i - E;
    int p = atomicAdd(&cursor[node], 1);
    esrc[p] = node;
  }
}

// ---------------------------------------------------------------- merged prep kernel
__device__ void transpose_dual_body(const float* __restrict__ Wa, int Na,
                                    const float* __restrict__ Wb, int Nb,
                                    int K, ushort_t* __restrict__ dst,
                                    int bxi, int byi, float (*tile)[33]) {
  const int bx = bxi * 32, by = byi * 32;
  const int tx = threadIdx.x & 31, ty = threadIdx.x >> 5;
  const bool isB = bx >= Na;
  const float* W = isB ? Wb : Wa;
  const int Nw = isB ? Nb : Na;
  const int nc = bx - (isB ? Na : 0) + tx;
  for (int i = ty; i < 32; i += 8)
    tile[i][tx] = W[(size_t)(by + i) * Nw + nc];
  __syncthreads();
  for (int i = ty; i < 32; i += 8)
    dst[(size_t)(bx + i) * K + by + tx] = f2bf(tile[tx][i]);
}

__global__ __launch_bounds__(256) void prep_k(const float* __restrict__ x, ushort_t* __restrict__ x_bf, int n4,
                                              const float* __restrict__ W1, const float* __restrict__ l1W, ushort_t* __restrict__ W1cat,
                                              const float* __restrict__ W2, const float* __restrict__ l2W, ushort_t* __restrict__ W2cat,
                                              const float* __restrict__ W3, const float* __restrict__ l3W, ushort_t* __restrict__ W3cat,
                                              const float* __restrict__ a3s, const float* __restrict__ a3d) {
  __shared__ float tile[32][33];
  const int b = blockIdx.x, t = threadIdx.x;
  if (b < 1250) {
    int i = b * 256 + t;
    if (i < n4) {
      float4 v = ((const float4*)x)[i];
      ushort_t* p = x_bf + i * 4;
      p[0] = f2bf(v.x); p[1] = f2bf(v.y); p[2] = f2bf(v.z); p[3] = f2bf(v.w);
    }
  } else if (b < 1506) {
    int lo = b - 1250;  // (64,4)
    transpose_dual_body(W1, 1024, l1W, 1024, 128, W1cat, lo % 64, lo / 64, tile);
  } else if (b < 3554) {
    int lo = b - 1506;  // (64,32)
    transpose_dual_body(W2, 1024, l2W, 1024, 1024, W2cat, lo % 64, lo / 64, tile);
  } else if (b < 4002) {
    int lo = b - 3554;  // (14,32)
    transpose_dual_body(W3, 384, l3W, 64, 1024, W3cat, lo % 14, lo / 14, tile);
  } else {
    int k = (b - 4002) * 256 + t;  // 0..1023
    const float* row = W3 + (size_t)k * 384;
    for (int hd = 0; hd < 6; ++hd) {
      float ss = 0.f, dd = 0.f;
      for (int c = 0; c < 64; ++c) {
        float w = row[hd * 64 + c];
        ss += w * a3s[hd * 64 + c];
        dd += w * a3d[hd * 64 + c];
      }
      W3cat[(size_t)(448 + hd) * 1024 + k] = f2bf(ss);
      W3cat[(size_t)(454 + hd) * 1024 + k] = f2bf(dd);
    }
    for (int j = 460; j < 512; ++j) W3cat[(size_t)j * 1024 + k] = 0;
  }
}

// ---------------------------------------------------------------- gemm320 v2: BM=320 BN=256 BK=64
// 1024 threads / 16 waves (4M x 4N), per-wave 80x64 -> acc[5][4] = 80 regs (no spill).
// Grid 8x32 = 256 blocks = 1 round. LDS 144KB double-buffered; k-slot XOR swizzle
// (8 slots of 16B per 128B row; LDS slot p of row r holds global slot p^(r&7)).
// Staging: 5 gload_lds/thread/tile (A rows 0-127,128-255,256-319[wid<8], B 0-127,128-255).
// One vmcnt(0)+raw-barrier per K-tile (640 MFMA/block/barrier). Epilogue via LDS
// transpose -> coalesced 32B row stores (kills partial-line write amplification).
template<int K, int HC, int SC, bool LOGITS>
__global__ __launch_bounds__(1024) void gemm320(const ushort_t* __restrict__ A,
                                                const ushort_t* __restrict__ BT,
                                                const float* __restrict__ skip_bias,
                                                const float* __restrict__ a_src,
                                                const float* __restrict__ a_dst,
                                                float* __restrict__ sb,
                                                float* __restrict__ db,
                                                ushort_t* __restrict__ h_out,
                                                ushort_t* __restrict__ skip_out,
                                                int M) {
  __shared__ ushort_t As[2 * 320 * 64];  // 80 KB
  __shared__ ushort_t Bs[2 * 256 * 64];  // 64 KB
  const int gx = gridDim.x;
  const int nwg = gx * (int)gridDim.y;
  const int orig = blockIdx.y * gx + blockIdx.x;
  const int q = nwg >> 3, r = nwg & 7, xcd = orig & 7;
  const int wgid = (xcd < r ? xcd * (q + 1) : r * (q + 1) + (xcd - r) * q) + (orig >> 3);
  const int bm = (wgid / gx) * 320, bn = (wgid % gx) * 256;

  const int t = threadIdx.x, l = t & 63, wid = t >> 6;
  const int wm = wid >> 2, wn = wid & 3;  // 4 x 4
  const int lr = l & 15, s4 = l >> 4;

  // staging: one call = 1024 lanes x 16B = 128 rows x 128B; row-in-call = t>>3, 16B-slot = t&7
  const int rowc = t >> 3;
  const int s_src = (t & 7) ^ (rowc & 7);  // inverse swizzle at the global source
  const int a0 = min(bm + rowc, M - 1) * K + s_src * 8;
  const int a1 = min(bm + 128 + rowc, M - 1) * K + s_src * 8;
  const int a2 = min(bm + 256 + rowc, M - 1) * K + s_src * 8;  // used by t<512 (rows 256..319)
  const int b0 = (bn + rowc) * K + s_src * 8;
  const int b1 = (bn + 128 + rowc) * K + s_src * 8;

  auto stage = [&](int tile) {
    const int buf = tile & 1;
    const int kc = tile * 64;
    ushort_t* ab = &As[buf * 320 * 64];
    ushort_t* bb = &Bs[buf * 256 * 64];
    gload_lds16(A + a0 + kc, ab + t * 8);
    gload_lds16(A + a1 + kc, ab + 128 * 64 + t * 8);
    if (t < 512) gload_lds16(A + a2 + kc, ab + 256 * 64 + t * 8);
    gload_lds16(BT + b0 + kc, bb + t * 8);
    gload_lds16(BT + b1 + kc, bb + 128 * 64 + t * 8);
  };

  f32x4 acc[5][4] = {};
  constexpr int T = K >> 6;

  stage(0);
  PIPE_BAR(0);
  for (int tile = 0; tile < T; ++tile) {
    const int aB = (tile & 1) * 320 * 64, bB = (tile & 1) * 256 * 64;
    if (tile + 1 < T) stage(tile + 1);
#pragma unroll
    for (int kk = 0; kk < 2; ++kk) {
      bf16x8 b[4];
#pragma unroll
      for (int n = 0; n < 4; ++n) {
        int rb = wn * 64 + n * 16 + lr;
        b[n] = *(const bf16x8*)&Bs[bB + rb * 64 + (((kk * 4 + s4) ^ (rb & 7)) << 3)];
      }
#pragma unroll
      for (int m = 0; m < 5; ++m) {
        int ra = wm * 80 + m * 16 + lr;
        bf16x8 a = *(const bf16x8*)&As[aB + ra * 64 + (((kk * 4 + s4) ^ (ra & 7)) << 3)];
        __builtin_amdgcn_s_setprio(1);
#pragma unroll
        for (int n = 0; n < 4; ++n)
          acc[m][n] = __builtin_amdgcn_mfma_f32_16x16x32_bf16(a, b[n], acc[m][n], 0, 0, 0);
        __builtin_amdgcn_s_setprio(0);
      }
    }
    PIPE_BAR(0);
  }

  // ---- fused logits (L1/L2): wave's 64 cols belong to one head
  const int colw = bn + wn * 64;
  if (LOGITS && colw < HC) {
    const int head = colw >> 8;
    float as[4], ad[4];
#pragma unroll
    for (int n = 0; n < 4; ++n) {
      int c = (colw + n * 16 + lr) & 255;
      as[n] = a_src[head * 256 + c];
      ad[n] = a_dst[head * 256 + c];
    }
#pragma unroll
    for (int m = 0; m < 5; ++m) {
#pragma unroll
      for (int j = 0; j < 4; ++j) {
        float sp = 0.f, dp = 0.f;
#pragma unroll
        for (int n = 0; n < 4; ++n) { sp += acc[m][n][j] * as[n]; dp += acc[m][n][j] * ad[n]; }
#pragma unroll
        for (int off = 1; off <= 8; off <<= 1) {
          sp += __shfl_xor(sp, off);
          dp += __shfl_xor(dp, off);
        }
        if (lr == 0) {
          int row = bm + wm * 80 + m * 16 + s4 * 4 + j;
          if (row < M) {
            atomicAdd(&sb[row * 4 + head], sp);
            atomicAdd(&db[row * 4 + head], dp);
          }
        }
      }
    }
  }

  // ---- epilogue: LDS transpose -> coalesced stores. Block is all-h or all-skip (BN=256).
  ushort_t* EP = As;  // 64 x 256 ushorts = 32 KB per chunk
  const bool isH = (bn < HC);
#pragma unroll
  for (int m = 0; m < 5; ++m) {
    __syncthreads();
#pragma unroll
    for (int n = 0; n < 4; ++n) {
      float bvn = isH ? 0.f : skip_bias[bn - HC + wn * 64 + n * 16 + lr];
#pragma unroll
      for (int j = 0; j < 4; ++j)
        EP[(wm * 16 + s4 * 4 + j) * 256 + wn * 64 + n * 16 + lr] = f2bf(acc[m][n][j] + bvn);
    }
    __syncthreads();
    const int r_l = t >> 4, c0 = (t & 15) * 16;
    const int grow = bm + (r_l >> 4) * 80 + m * 16 + (r_l & 15);
    if (grow < M) {
      const ushort_t* srcp = &EP[r_l * 256 + c0];
      ushort_t* dst = isH ? &h_out[(size_t)grow * HC + bn + c0]
                          : &skip_out[(size_t)grow * SC + (bn - HC) + c0];
      *(uint4*)dst = *(const uint4*)srcp;
      *(uint4*)(dst + 8) = *(const uint4*)(srcp + 8);
    }
  }
}

// ---------------------------------------------------------------- 128x128 ring GEMM (L3)
template<int NCT, int HC, int SC, bool SD_COLS>
__global__ __launch_bounds__(256) void gemm_fused(const ushort_t* __restrict__ A,
                                                  const ushort_t* __restrict__ BT,
                                                  const float* __restrict__ skip_bias,
                                                  float* __restrict__ sb,
                                                  float* __restrict__ db,
                                                  ushort_t* __restrict__ h_out,
                                                  float* __restrict__ skip_out,
                                                  int M, int K) {
  __shared__ ushort_t As[4][128 * 32];
  __shared__ ushort_t Bs[4][128 * 32];
  const int gx = gridDim.x;
  const int nwg = gx * (int)gridDim.y;
  const int orig = blockIdx.y * gx + blockIdx.x;
  const int q = nwg >> 3, r = nwg & 7, xcd = orig & 7;
  const int wgid = (xcd < r ? xcd * (q + 1) : r * (q + 1) + (xcd - r) * q) + (orig >> 3);
  const int bm = (wgid / gx) * 128, bn = (wgid % gx) * 128;

  const int t = threadIdx.x;
  const int l = t & 63, wid = t >> 6;
  const int wm = wid >> 1, wn = wid & 1;

  size_t goffA[2], goffB[2];
  for (int i = 0; i < 2; ++i) {
    int seg = wid * 2 + i;
    int row = seg * 16 + (l >> 2);
    int p = l & 3;
    int ls = p ^ ((row >> 1) & 3);
    int ga = min(bm + row, M - 1);
    int gb = min(bn + row, NCT - 1);
    goffA[i] = (size_t)ga * K + ls * 8;
    goffB[i] = (size_t)gb * K + ls * 8;
  }

  const int lr = l & 15, s = l >> 4;
  int raddrA[4], raddrB[4];
  for (int m = 0; m < 4; ++m) {
    int rowA = wm * 64 + m * 16 + lr;
    raddrA[m] = rowA * 32 + (s ^ ((rowA >> 1) & 3)) * 8;
    int rowB = wn * 64 + m * 16 + lr;
    raddrB[m] = rowB * 32 + (s ^ ((rowB >> 1) & 3)) * 8;
  }

  f32x4 acc[4][4] = {};
  auto stage = [&](int st) {
    int buf = st & 3;
    int k0 = st * 32;
    gload_lds16(A + goffA[0] + k0, &As[buf][(wid * 2 + 0) * 512]);
    gload_lds16(A + goffA[1] + k0, &As[buf][(wid * 2 + 1) * 512]);
    gload_lds16(BT + goffB[0] + k0, &Bs[buf][(wid * 2 + 0) * 512]);
    gload_lds16(BT + goffB[1] + k0, &Bs[buf][(wid * 2 + 1) * 512]);
  };
  auto body = [&](int st) {
    int buf = st & 3;
    bf16x8 a[4], b[4];
#pragma unroll
    for (int m = 0; m < 4; ++m) a[m] = *(const bf16x8*)&As[buf][raddrA[m]];
#pragma unroll
    for (int n = 0; n < 4; ++n) b[n] = *(const bf16x8*)&Bs[buf][raddrB[n]];
#pragma unroll
    for (int m = 0; m < 4; ++m)
#pragma unroll
      for (int n = 0; n < 4; ++n)
        acc[m][n] = __builtin_amdgcn_mfma_f32_16x16x32_bf16(a[m], b[n], acc[m][n], 0, 0, 0);
  };

  const int T = K >> 5;
  stage(0); stage(1); stage(2);
  int st = 0;
  for (; st < T - 3; ++st) {
    PIPE_BAR(8);
    body(st);
    stage(st + 3);
  }
  PIPE_BAR(8); body(T - 3);
  PIPE_BAR(4); body(T - 2);
  PIPE_BAR(0); body(T - 1);

#pragma unroll
  for (int n = 0; n < 4; ++n) {
    int col = bn + wn * 64 + n * 16 + lr;
    if (col >= HC + SC + (SD_COLS ? 12 : 0)) continue;
    const bool is_h = col < HC;
    const bool is_skip = !is_h && col < HC + SC;
    float bv = is_skip ? skip_bias[col - HC] : 0.f;
#pragma unroll
    for (int m = 0; m < 4; ++m) {
#pragma unroll
      for (int j = 0; j < 4; ++j) {
        int row = bm + wm * 64 + m * 16 + (l >> 4) * 4 + j;
        if (row >= M) continue;
        float v = acc[m][n][j] + bv;
        if (is_h) {
          h_out[(size_t)row * HC + col] = f2bf(v);
        } else if (is_skip) {
          skip_out[(size_t)row * SC + (col - HC)] = v;
        } else if (SD_COLS) {
          int jj = col - (HC + SC);
          if (jj < 6) sb[row * 6 + jj] = v;
          else        db[row * 6 + (jj - 6)] = v;
        }
      }
    }
  }
}

// ---------------------------------------------------------------- attention + aggregate
template<int H, int C, bool ELU_OUT, bool MEAN_HEADS>
__global__ __launch_bounds__(256) void attn_k(const ushort_t* __restrict__ hfeat,
                                              const float* __restrict__ sbuf,
                                              const float* __restrict__ dbuf,
                                              const int* __restrict__ indptr,
                                              const int* __restrict__ esrc,
                                              const float* __restrict__ bias,
                                              const void* __restrict__ skip_v,
                                              void* __restrict__ out_v) {
  constexpr int F = H * C;
  constexpr int CPT = (F + 255) / 256;
  constexpr int CH = 256 / H;
  __shared__ float m_l[H], invden_l[H], d_l[H];
  __shared__ float alpha_l[CH * H];
  __shared__ int src_l[CH];
  __shared__ float accs[MEAN_HEADS ? F : 4];

  const int node = blockIdx.x;
  const int t = threadIdx.x;
  const int beg = indptr[node];
  const int deg = indptr[node + 1] - beg;
  if (t < H) d_l[t] = dbuf[node * H + t];
  __syncthreads();

  const int wave = t >> 6, lane = t & 63;
  for (int hd = wave; hd < H; hd += 4) {
    const float dn = d_l[hd];
    float mx = -1e30f;
    for (int i = lane; i < deg; i += 64) {
      int se = esrc[beg + i];
      float e = sbuf[se * H + hd] + dn;
      e = fmaxf(e, 0.2f * e);
      mx = fmaxf(mx, e);
    }
    for (int off = 32; off; off >>= 1) mx = fmaxf(mx, __shfl_xor(mx, off));
    float den = 0.f;
    for (int i = lane; i < deg; i += 64) {
      int se = esrc[beg + i];
      float e = sbuf[se * H + hd] + dn;
      e = fmaxf(e, 0.2f * e);
      den += __expf(e - mx);
    }
    for (int off = 32; off; off >>= 1) den += __shfl_xor(den, off);
    if (lane == 0) { m_l[hd] = mx; invden_l[hd] = 1.f / den; }
  }
  __syncthreads();

  float acc[CPT] = {};
  const int c0 = t * CPT;
  const int myhead = c0 / C;
  for (int cb = 0; cb < deg; cb += CH) {
    const int ce = min(CH, deg - cb);
    if (t < ce * H) {
      int e_i = t / H, hd = t % H;
      int se = esrc[beg + cb + e_i];
      if (hd == 0) src_l[e_i] = se;
      float e = sbuf[se * H + hd] + d_l[hd];
      e = fmaxf(e, 0.2f * e);
      alpha_l[e_i * H + hd] = __expf(e - m_l[hd]) * invden_l[hd];
    }
    __syncthreads();
    if (c0 < F) {
      for (int e_i = 0; e_i < ce; ++e_i) {
        int se = src_l[e_i];
        float al = alpha_l[e_i * H + myhead];
        const ushort_t* hp = hfeat + (size_t)se * F + c0;
        if (CPT == 4) {
          ushort4 v = *(const ushort4*)hp;
          acc[0] += al * bf2f(v.x); acc[1] += al * bf2f(v.y);
          acc[2] += al * bf2f(v.z); acc[3] += al * bf2f(v.w);
        } else {
          ushort2 v = *(const ushort2*)hp;
          acc[0] += al * bf2f(v.x); acc[1] += al * bf2f(v.y);
        }
      }
    }
    __syncthreads();
  }

  if (!MEAN_HEADS) {
    if (c0 < F) {
      const ushort_t* skip = (const ushort_t*)skip_v;
      ushort_t* out = (ushort_t*)out_v;
      ushort4 sv = *(const ushort4*)&skip[(size_t)node * F + c0];
      float sk[4] = {bf2f(sv.x), bf2f(sv.y), bf2f(sv.z), bf2f(sv.w)};
      ushort_t rr[CPT];
#pragma unroll
      for (int j = 0; j < CPT; ++j) {
        float xo = acc[j] + bias[c0 + j] + sk[j];
        if (ELU_OUT) xo = xo > 0.f ? xo : __expf(xo) - 1.f;
        rr[j] = f2bf(xo);
      }
      ushort4 o; o.x = rr[0]; o.y = rr[1]; o.z = rr[2]; o.w = rr[3];
      *(ushort4*)&out[(size_t)node * F + c0] = o;
    }
  } else {
    const float* skip = (const float*)skip_v;
    float* out = (float*)out_v;
    if (c0 < F) { accs[c0] = acc[0]; accs[c0 + 1] = acc[1]; }
    __syncthreads();
    if (t < C) {
      float sum = 0.f;
#pragma unroll
      for (int hd = 0; hd < H; ++hd) sum += accs[hd * C + t];
      out[(size_t)node * C + t] = sum * (1.f / (float)H) + bias[t] + skip[(size_t)node * C + t];
    }
  }
}

// ---------------------------------------------------------------- launch
extern "C" void kernel_launch(void* const* d_in, const int* in_sizes, int n_in,
                              void* d_out, int out_size, void* d_ws, size_t ws_size,
                              hipStream_t stream) {
  const float* x      = (const float*)d_in[0];
  const int*   ei     = (const int*)d_in[1];
  const float* W1     = (const float*)d_in[2];
  const float* a1s    = (const float*)d_in[3];
  const float* a1d    = (const float*)d_in[4];
  const float* b1     = (const float*)d_in[5];
  const float* lin1W  = (const float*)d_in[6];
  const float* lin1b  = (const float*)d_in[7];
  const float* W2     = (const float*)d_in[8];
  const float* a2s    = (const float*)d_in[9];
  const float* a2d    = (const float*)d_in[10];
  const float* b2     = (const float*)d_in[11];
  const float* lin2W  = (const float*)d_in[12];
  const float* lin2b  = (const float*)d_in[13];
  const float* W3     = (const float*)d_in[14];
  const float* a3s    = (const float*)d_in[15];
  const float* a3d    = (const float*)d_in[16];
  const float* b3     = (const float*)d_in[17];
  const float* lin3W  = (const float*)d_in[18];
  const float* lin3b  = (const float*)d_in[19];

  const int N = in_sizes[0] / 128;
  const int E = in_sizes[1] / 2;
  const int* src = ei;
  const int* dst = ei + E;

  char* ws = (char*)d_ws;
  size_t off = 0;
  auto alloc = [&](size_t bytes) -> void* {
    void* p = ws + off;
    off += (bytes + 255) & ~(size_t)255;
    return p;
  };
  ushort_t* h_bf    = (ushort_t*)alloc((size_t)N * 1024 * 2);
  ushort_t* skip_bf = (ushort_t*)alloc((size_t)N * 1024 * 2);
  float*    skip3   = (float*)alloc((size_t)N * 64 * 4);
  ushort_t* act_bf  = (ushort_t*)alloc((size_t)N * 1024 * 2);
  ushort_t* x_bf    = (ushort_t*)alloc((size_t)N * 128 * 2);
  ushort_t* W1cat   = (ushort_t*)alloc((size_t)2048 * 128 * 2);
  ushort_t* W2cat   = (ushort_t*)alloc((size_t)2048 * 1024 * 2);
  ushort_t* W3cat   = (ushort_t*)alloc((size_t)512 * 1024 * 2);
  float*    sd12    = (float*)alloc((size_t)4 * N * 4 * 4);
  float*    sb1 = sd12, *db1 = sd12 + N * 4, *sb2 = sd12 + 2 * N * 4, *db2 = sd12 + 3 * N * 4;
  float*    sb3     = (float*)alloc((size_t)N * 6 * 4);
  float*    db3     = (float*)alloc((size_t)N * 6 * 4);
  int*      indptr  = (int*)alloc((size_t)(N + 1) * 4);
  int*      cursor  = (int*)alloc((size_t)N * 4);
  int*      esrc    = (int*)alloc((size_t)(E + N) * 4);

  const int n4 = N * 128 / 4;
  prep_k<<<4006, 256, 0, stream>>>(x, x_bf, n4, W1, lin1W, W1cat, W2, lin2W, W2cat,
                                   W3, lin3W, W3cat, a3s, a3d);

  const int NZ = 4 * N * 4;
  init_k<<<(max(N, NZ) + 255) / 256, 256, 0, stream>>>(cursor, N, sd12, NZ);
  count_edges_k<<<(E + 255) / 256, 256, 0, stream>>>(dst, E, cursor);
  scan_k<<<1, 1024, 0, stream>>>(cursor, indptr, cursor, N);
  scatter_k<<<(E + N + 255) / 256, 256, 0, stream>>>(src, dst, E, N, cursor, esrc);

  const int MB  = (N + 127) / 128;
  const int MB3 = (N + 319) / 320;
  // ---- Layer 1 (K=128)
  gemm320<128, 1024, 1024, true><<<dim3(8, MB3), 1024, 0, stream>>>(
      x_bf, W1cat, lin1b, a1s, a1d, sb1, db1, h_bf, skip_bf, N);
  attn_k<4, 256, true, false><<<N, 256, 0, stream>>>(h_bf, sb1, db1, indptr, esrc, b1, skip_bf, act_bf);
  // ---- Layer 2 (K=1024)
  gemm320<1024, 1024, 1024, true><<<dim3(8, MB3), 1024, 0, stream>>>(
      act_bf, W2cat, lin2b, a2s, a2d, sb2, db2, h_bf, skip_bf, N);
  attn_k<4, 256, true, false><<<N, 256, 0, stream>>>(h_bf, sb2, db2, indptr, esrc, b2, skip_bf, act_bf);
  // ---- Layer 3 (128x128 ring; logits via folded cols 448..459)
  gemm_fused<512, 384, 64, true><<<dim3(4, MB), 256, 0, stream>>>(
      act_bf, W3cat, lin3b, sb3, db3, h_bf, skip3, N, 1024);
  attn_k<6, 64, false, true><<<N, 256, 0, stream>>>(h_bf, sb3, db3, indptr, esrc, b3, skip3, d_out);
}

// Round 10
// 341.818 us; speedup vs baseline: 1.2898x; 1.0016x over previous
//
#include <hip/hip_runtime.h>
#include <math.h>

typedef unsigned short ushort_t;
typedef __attribute__((ext_vector_type(8))) short bf16x8;
typedef __attribute__((ext_vector_type(4))) float f32x4;

__device__ __forceinline__ ushort_t f2bf(float f) {
  unsigned u = __float_as_uint(f);
  unsigned r = (u + 0x7FFF + ((u >> 16) & 1)) >> 16;  // RNE
  return (ushort_t)r;
}
__device__ __forceinline__ float bf2f(ushort_t u) {
  return __uint_as_float(((unsigned)u) << 16);
}

__device__ __forceinline__ void gload_lds16(const void* g, void* l) {
  __builtin_amdgcn_global_load_lds(
      (const __attribute__((address_space(1))) void*)g,
      (__attribute__((address_space(3))) void*)l, 16, 0, 0);
}

#define PIPE_BAR(N)                                          \
  do {                                                       \
    asm volatile("s_waitcnt vmcnt(" #N ")" ::: "memory");    \
    __builtin_amdgcn_s_barrier();                            \
    asm volatile("" ::: "memory");                           \
  } while (0)

// counted wait with per-wave load count (waves 0-3 stage 3 instrs/phase, others 2)
#define WAITC(n3, n2)                                        \
  do {                                                       \
    if (wlow) asm volatile("s_waitcnt vmcnt(" #n3 ")" ::: "memory"); \
    else      asm volatile("s_waitcnt vmcnt(" #n2 ")" ::: "memory"); \
    __builtin_amdgcn_s_barrier();                            \
    asm volatile("" ::: "memory");                           \
  } while (0)

// ---------------------------------------------------------------- CSR
__global__ void init_k(int* __restrict__ cursor, int n, float* __restrict__ z, int nz) {
  int i = blockIdx.x * blockDim.x + threadIdx.x;
  if (i < n) cursor[i] = 1;  // self-loop
  if (i < nz) z[i] = 0.f;
}

__global__ void count_edges_k(const int* __restrict__ dst, int E, int* __restrict__ cnt) {
  int i = blockIdx.x * blockDim.x + threadIdx.x;
  if (i < E) atomicAdd(&cnt[dst[i]], 1);
}

// exclusive scan via wave shuffles; writes indptr AND cursor
__global__ void scan_k(const int* __restrict__ cnt, int* __restrict__ indptr,
                       int* __restrict__ cursor, int n) {
  __shared__ int wsum[16];
  __shared__ int carry_s;
  const int t = threadIdx.x, lane = t & 63, w = t >> 6;
  if (t == 0) carry_s = 0;
  __syncthreads();
  for (int base = 0; base < n; base += 1024) {
    int i = base + t;
    int v = (i < n) ? cnt[i] : 0;
    int x = v;
#pragma unroll
    for (int off = 1; off < 64; off <<= 1) {
      int y = __shfl_up(x, off);
      if (lane >= off) x += y;
    }
    if (lane == 63) wsum[w] = x;
    __syncthreads();
    if (w == 0 && lane < 16) {
      int y = wsum[lane];
#pragma unroll
      for (int off = 1; off < 16; off <<= 1) {
        int z = __shfl_up(y, off);
        if (lane >= off) y += z;
      }
      wsum[lane] = y;
    }
    __syncthreads();
    int woff = (w == 0) ? 0 : wsum[w - 1];
    int carry = carry_s;
    int incl = x + woff + carry;
    if (i < n) { indptr[i] = incl - v; cursor[i] = incl - v; }
    __syncthreads();
    if (t == 1023) carry_s = incl;
    __syncthreads();
  }
  if (threadIdx.x == 0) indptr[n] = carry_s;
}

__global__ void scatter_k(const int* __restrict__ src, const int* __restrict__ dst, int E, int n,
                          int* __restrict__ cursor, int* __restrict__ esrc) {
  int i = blockIdx.x * blockDim.x + threadIdx.x;
  if (i < E) {
    int p = atomicAdd(&cursor[dst[i]], 1);
    esrc[p] = src[i];
  } else if (i < E + n) {
    int node = i - E;
    int p = atomicAdd(&cursor[node], 1);
    esrc[p] = node;
  }
}

// ---------------------------------------------------------------- merged prep kernel
__device__ void transpose_dual_body(const float* __restrict__ Wa, int Na,
                                    const float* __restrict__ Wb, int Nb,
                                    int K, ushort_t* __restrict__ dst,
                                    int bxi, int byi, float (*tile)[33]) {
  const int bx = bxi * 32, by = byi * 32;
  const int tx = threadIdx.x & 31, ty = threadIdx.x >> 5;
  const bool isB = bx >= Na;
  const float* W = isB ? Wb : Wa;
  const int Nw = isB ? Nb : Na;
  const int nc = bx - (isB ? Na : 0) + tx;
  for (int i = ty; i < 32; i += 8)
    tile[i][tx] = W[(size_t)(by + i) * Nw + nc];
  __syncthreads();
  for (int i = ty; i < 32; i += 8)
    dst[(size_t)(bx + i) * K + by + tx] = f2bf(tile[tx][i]);
}

__global__ __launch_bounds__(256) void prep_k(const float* __restrict__ x, ushort_t* __restrict__ x_bf, int n4,
                                              const float* __restrict__ W1, const float* __restrict__ l1W, ushort_t* __restrict__ W1cat,
                                              const float* __restrict__ W2, const float* __restrict__ l2W, ushort_t* __restrict__ W2cat,
                                              const float* __restrict__ W3, const float* __restrict__ l3W, ushort_t* __restrict__ W3cat,
                                              const float* __restrict__ a3s, const float* __restrict__ a3d) {
  __shared__ float tile[32][33];
  const int b = blockIdx.x, t = threadIdx.x;
  if (b < 1250) {
    int i = b * 256 + t;
    if (i < n4) {
      float4 v = ((const float4*)x)[i];
      ushort_t* p = x_bf + i * 4;
      p[0] = f2bf(v.x); p[1] = f2bf(v.y); p[2] = f2bf(v.z); p[3] = f2bf(v.w);
    }
  } else if (b < 1506) {
    int lo = b - 1250;  // (64,4)
    transpose_dual_body(W1, 1024, l1W, 1024, 128, W1cat, lo % 64, lo / 64, tile);
  } else if (b < 3554) {
    int lo = b - 1506;  // (64,32)
    transpose_dual_body(W2, 1024, l2W, 1024, 1024, W2cat, lo % 64, lo / 64, tile);
  } else if (b < 4002) {
    int lo = b - 3554;  // (14,32)
    transpose_dual_body(W3, 384, l3W, 64, 1024, W3cat, lo % 14, lo / 14, tile);
  } else {
    int k = (b - 4002) * 256 + t;  // 0..1023
    const float* row = W3 + (size_t)k * 384;
    for (int hd = 0; hd < 6; ++hd) {
      float ss = 0.f, dd = 0.f;
      for (int c = 0; c < 64; ++c) {
        float w = row[hd * 64 + c];
        ss += w * a3s[hd * 64 + c];
        dd += w * a3d[hd * 64 + c];
      }
      W3cat[(size_t)(448 + hd) * 1024 + k] = f2bf(ss);
      W3cat[(size_t)(454 + hd) * 1024 + k] = f2bf(dd);
    }
    for (int j = 460; j < 512; ++j) W3cat[(size_t)j * 1024 + k] = 0;
  }
}

// ---------------------------------------------------------------- gemm320 v3: 4-deep half-phase ring
// BM=320 BN=256 BK=64, 1024 thr / 16 waves (4M x 4N), acc[5][4]. Grid 8x32 = 256 blocks (1 round).
// Phases p = 2*tile+kk. LDS = 4 half-regions: A[4][320][32], B[4][256][32] (144 KB), region = p&3.
// Swizzle (proven, 0-conflict): LDS slot s of row r holds global 16B-slot s^((r>>1)&3).
// Each phase: 9 ds_read_b128 || stage half p+3 (3 or 2 gload_lds/wave) || 20 MFMA; barrier waits
// COUNTED vmcnt (2 halves stay in flight across barriers; drains only in the 2-phase tail).
template<int K, int HC, int SC, bool LOGITS>
__global__ __launch_bounds__(1024) void gemm320(const ushort_t* __restrict__ A,
                                                const ushort_t* __restrict__ BT,
                                                const float* __restrict__ skip_bias,
                                                const float* __restrict__ a_src,
                                                const float* __restrict__ a_dst,
                                                float* __restrict__ sb,
                                                float* __restrict__ db,
                                                ushort_t* __restrict__ h_out,
                                                ushort_t* __restrict__ skip_out,
                                                int M) {
  __shared__ ushort_t As[4 * 320 * 32];  // 80 KB
  __shared__ ushort_t Bs[4 * 256 * 32];  // 64 KB
  const int gx = gridDim.x;
  const int nwg = gx * (int)gridDim.y;
  const int orig = blockIdx.y * gx + blockIdx.x;
  const int q = nwg >> 3, r = nwg & 7, xcd = orig & 7;
  const int wgid = (xcd < r ? xcd * (q + 1) : r * (q + 1) + (xcd - r) * q) + (orig >> 3);
  const int bm = (wgid / gx) * 320, bn = (wgid % gx) * 256;

  const int t = threadIdx.x, l = t & 63, wid = t >> 6;
  const bool wlow = (wid < 4);            // these waves issue 3 staging loads/phase, others 2
  const int wm = wid >> 2, wn = wid & 3;  // 4 x 4
  const int lr = l & 15, s4 = l >> 4;

  // staging addresses: call covers 256 rows x 4 slots; row = t>>2, LDS slot = t&3,
  // global slot = (t&3) ^ ((row>>1)&3)  (inverse of the read-side swizzle)
  const int rowc = t >> 2;
  const int sl0 = (t & 3) ^ ((rowc >> 1) & 3);
  const int rc1 = 256 + rowc;  // only t<256 (waves 0-3)
  const int sl1 = (t & 3) ^ ((rc1 >> 1) & 3);
  const int a0 = min(bm + rowc, M - 1) * K + sl0 * 8;
  const int a1 = min(bm + rc1, M - 1) * K + sl1 * 8;
  const int b0 = (bn + rowc) * K + sl0 * 8;

  auto stage_half = [&](int p) {
    const int reg4 = p & 3;
    const int kc = p * 32;  // global k offset (ushorts): tile*64 + kk*32
    ushort_t* ar = &As[reg4 * (320 * 32)];
    ushort_t* br = &Bs[reg4 * (256 * 32)];
    gload_lds16(A + a0 + kc, ar + t * 8);                         // A rows 0..255
    if (t < 256) gload_lds16(A + a1 + kc, ar + 256 * 32 + t * 8); // A rows 256..319
    gload_lds16(BT + b0 + kc, br + t * 8);                        // B rows 0..255
  };

  f32x4 acc[5][4] = {};

  auto body = [&](int p) {
    const int aB = (p & 3) * (320 * 32), bB = (p & 3) * (256 * 32);
    bf16x8 b[4];
#pragma unroll
    for (int n = 0; n < 4; ++n) {
      int rb = wn * 64 + n * 16 + lr;
      b[n] = *(const bf16x8*)&Bs[bB + rb * 32 + ((s4 ^ ((rb >> 1) & 3)) << 3)];
    }
    bf16x8 a[5];
#pragma unroll
    for (int m = 0; m < 5; ++m) {
      int ra = wm * 80 + m * 16 + lr;
      a[m] = *(const bf16x8*)&As[aB + ra * 32 + ((s4 ^ ((ra >> 1) & 3)) << 3)];
    }
    if (p + 3 < (K >> 5)) stage_half(p + 3);
    __builtin_amdgcn_s_setprio(1);
#pragma unroll
    for (int m = 0; m < 5; ++m)
#pragma unroll
      for (int n = 0; n < 4; ++n)
        acc[m][n] = __builtin_amdgcn_mfma_f32_16x16x32_bf16(a[m], b[n], acc[m][n], 0, 0, 0);
    __builtin_amdgcn_s_setprio(0);
  };

  constexpr int NP = K >> 5;  // phases (half-tiles of BK=32); K=1024 -> 32, K=128 -> 4
  stage_half(0); stage_half(1); stage_half(2);
  for (int p = 0; p < NP - 2; ++p) {
    WAITC(6, 4);   // own S(p) landed; S(p+1),S(p+2) stay in flight
    body(p);
  }
  WAITC(3, 2); body(NP - 2);
  WAITC(0, 0); body(NP - 1);

  // ---- fused logits (L1/L2): wave's 64 cols belong to one head
  const int colw = bn + wn * 64;
  if (LOGITS && colw < HC) {
    const int head = colw >> 8;
    float as[4], ad[4];
#pragma unroll
    for (int n = 0; n < 4; ++n) {
      int c = (colw + n * 16 + lr) & 255;
      as[n] = a_src[head * 256 + c];
      ad[n] = a_dst[head * 256 + c];
    }
#pragma unroll
    for (int m = 0; m < 5; ++m) {
#pragma unroll
      for (int j = 0; j < 4; ++j) {
        float sp = 0.f, dp = 0.f;
#pragma unroll
        for (int n = 0; n < 4; ++n) { sp += acc[m][n][j] * as[n]; dp += acc[m][n][j] * ad[n]; }
#pragma unroll
        for (int off = 1; off <= 8; off <<= 1) {
          sp += __shfl_xor(sp, off);
          dp += __shfl_xor(dp, off);
        }
        if (lr == 0) {
          int row = bm + wm * 80 + m * 16 + s4 * 4 + j;
          if (row < M) {
            atomicAdd(&sb[row * 4 + head], sp);
            atomicAdd(&db[row * 4 + head], dp);
          }
        }
      }
    }
  }

  // ---- epilogue: LDS transpose -> coalesced 32B row stores. Block all-h or all-skip (BN=256).
  ushort_t* EP = As;  // 64 x 256 ushorts = 32 KB
  const bool isH = (bn < HC);
#pragma unroll
  for (int m = 0; m < 5; ++m) {
    __syncthreads();
#pragma unroll
    for (int n = 0; n < 4; ++n) {
      float bvn = isH ? 0.f : skip_bias[bn - HC + wn * 64 + n * 16 + lr];
#pragma unroll
      for (int j = 0; j < 4; ++j)
        EP[(wm * 16 + s4 * 4 + j) * 256 + wn * 64 + n * 16 + lr] = f2bf(acc[m][n][j] + bvn);
    }
    __syncthreads();
    const int r_l = t >> 4, c0 = (t & 15) * 16;
    const int grow = bm + (r_l >> 4) * 80 + m * 16 + (r_l & 15);
    if (grow < M) {
      const ushort_t* srcp = &EP[r_l * 256 + c0];
      ushort_t* dst = isH ? &h_out[(size_t)grow * HC + bn + c0]
                          : &skip_out[(size_t)grow * SC + (bn - HC) + c0];
      *(uint4*)dst = *(const uint4*)srcp;
      *(uint4*)(dst + 8) = *(const uint4*)(srcp + 8);
    }
  }
}

// ---------------------------------------------------------------- 128x128 ring GEMM (L3)
template<int NCT, int HC, int SC, bool SD_COLS>
__global__ __launch_bounds__(256) void gemm_fused(const ushort_t* __restrict__ A,
                                                  const ushort_t* __restrict__ BT,
                                                  const float* __restrict__ skip_bias,
                                                  float* __restrict__ sb,
                                                  float* __restrict__ db,
                                                  ushort_t* __restrict__ h_out,
                                                  float* __restrict__ skip_out,
                                                  int M, int K) {
  __shared__ ushort_t As[4][128 * 32];
  __shared__ ushort_t Bs[4][128 * 32];
  const int gx = gridDim.x;
  const int nwg = gx * (int)gridDim.y;
  const int orig = blockIdx.y * gx + blockIdx.x;
  const int q = nwg >> 3, r = nwg & 7, xcd = orig & 7;
  const int wgid = (xcd < r ? xcd * (q + 1) : r * (q + 1) + (xcd - r) * q) + (orig >> 3);
  const int bm = (wgid / gx) * 128, bn = (wgid % gx) * 128;

  const int t = threadIdx.x;
  const int l = t & 63, wid = t >> 6;
  const int wm = wid >> 1, wn = wid & 1;

  size_t goffA[2], goffB[2];
  for (int i = 0; i < 2; ++i) {
    int seg = wid * 2 + i;
    int row = seg * 16 + (l >> 2);
    int p = l & 3;
    int ls = p ^ ((row >> 1) & 3);
    int ga = min(bm + row, M - 1);
    int gb = min(bn + row, NCT - 1);
    goffA[i] = (size_t)ga * K + ls * 8;
    goffB[i] = (size_t)gb * K + ls * 8;
  }

  const int lr = l & 15, s = l >> 4;
  int raddrA[4], raddrB[4];
  for (int m = 0; m < 4; ++m) {
    int rowA = wm * 64 + m * 16 + lr;
    raddrA[m] = rowA * 32 + (s ^ ((rowA >> 1) & 3)) * 8;
    int rowB = wn * 64 + m * 16 + lr;
    raddrB[m] = rowB * 32 + (s ^ ((rowB >> 1) & 3)) * 8;
  }

  f32x4 acc[4][4] = {};
  auto stage = [&](int st) {
    int buf = st & 3;
    int k0 = st * 32;
    gload_lds16(A + goffA[0] + k0, &As[buf][(wid * 2 + 0) * 512]);
    gload_lds16(A + goffA[1] + k0, &As[buf][(wid * 2 + 1) * 512]);
    gload_lds16(BT + goffB[0] + k0, &Bs[buf][(wid * 2 + 0) * 512]);
    gload_lds16(BT + goffB[1] + k0, &Bs[buf][(wid * 2 + 1) * 512]);
  };
  auto body = [&](int st) {
    int buf = st & 3;
    bf16x8 a[4], b[4];
#pragma unroll
    for (int m = 0; m < 4; ++m) a[m] = *(const bf16x8*)&As[buf][raddrA[m]];
#pragma unroll
    for (int n = 0; n < 4; ++n) b[n] = *(const bf16x8*)&Bs[buf][raddrB[n]];
#pragma unroll
    for (int m = 0; m < 4; ++m)
#pragma unroll
      for (int n = 0; n < 4; ++n)
        acc[m][n] = __builtin_amdgcn_mfma_f32_16x16x32_bf16(a[m], b[n], acc[m][n], 0, 0, 0);
  };

  const int T = K >> 5;
  stage(0); stage(1); stage(2);
  int st = 0;
  for (; st < T - 3; ++st) {
    PIPE_BAR(8);
    body(st);
    stage(st + 3);
  }
  PIPE_BAR(8); body(T - 3);
  PIPE_BAR(4); body(T - 2);
  PIPE_BAR(0); body(T - 1);

#pragma unroll
  for (int n = 0; n < 4; ++n) {
    int col = bn + wn * 64 + n * 16 + lr;
    if (col >= HC + SC + (SD_COLS ? 12 : 0)) continue;
    const bool is_h = col < HC;
    const bool is_skip = !is_h && col < HC + SC;
    float bv = is_skip ? skip_bias[col - HC] : 0.f;
#pragma unroll
    for (int m = 0; m < 4; ++m) {
#pragma unroll
      for (int j = 0; j < 4; ++j) {
        int row = bm + wm * 64 + m * 16 + (l >> 4) * 4 + j;
        if (row >= M) continue;
        float v = acc[m][n][j] + bv;
        if (is_h) {
          h_out[(size_t)row * HC + col] = f2bf(v);
        } else if (is_skip) {
          skip_out[(size_t)row * SC + (col - HC)] = v;
        } else if (SD_COLS) {
          int jj = col - (HC + SC);
          if (jj < 6) sb[row * 6 + jj] = v;
          else        db[row * 6 + (jj - 6)] = v;
        }
      }
    }
  }
}

// ---------------------------------------------------------------- attention + aggregate
template<int H, int C, bool ELU_OUT, bool MEAN_HEADS>
__global__ __launch_bounds__(256) void attn_k(const ushort_t* __restrict__ hfeat,
                                              const float* __restrict__ sbuf,
                                              const float* __restrict__ dbuf,
                                              const int* __restrict__ indptr,
                                              const int* __restrict__ esrc,
                                              const float* __restrict__ bias,
                                              const void* __restrict__ skip_v,
                                              void* __restrict__ out_v) {
  constexpr int F = H * C;
  constexpr int CPT = (F + 255) / 256;
  constexpr int CH = 256 / H;
  __shared__ float m_l[H], invden_l[H], d_l[H];
  __shared__ float alpha_l[CH * H];
  __shared__ int src_l[CH];
  __shared__ float accs[MEAN_HEADS ? F : 4];

  const int node = blockIdx.x;
  const int t = threadIdx.x;
  const int beg = indptr[node];
  const int deg = indptr[node + 1] - beg;
  if (t < H) d_l[t] = dbuf[node * H + t];
  __syncthreads();

  const int wave = t >> 6, lane = t & 63;
  for (int hd = wave; hd < H; hd += 4) {
    const float dn = d_l[hd];
    float mx = -1e30f;
    for (int i = lane; i < deg; i += 64) {
      int se = esrc[beg + i];
      float e = sbuf[se * H + hd] + dn;
      e = fmaxf(e, 0.2f * e);
      mx = fmaxf(mx, e);
    }
    for (int off = 32; off; off >>= 1) mx = fmaxf(mx, __shfl_xor(mx, off));
    float den = 0.f;
    for (int i = lane; i < deg; i += 64) {
      int se = esrc[beg + i];
      float e = sbuf[se * H + hd] + dn;
      e = fmaxf(e, 0.2f * e);
      den += __expf(e - mx);
    }
    for (int off = 32; off; off >>= 1) den += __shfl_xor(den, off);
    if (lane == 0) { m_l[hd] = mx; invden_l[hd] = 1.f / den; }
  }
  __syncthreads();

  float acc[CPT] = {};
  const int c0 = t * CPT;
  const int myhead = c0 / C;
  for (int cb = 0; cb < deg; cb += CH) {
    const int ce = min(CH, deg - cb);
    if (t < ce * H) {
      int e_i = t / H, hd = t % H;
      int se = esrc[beg + cb + e_i];
      if (hd == 0) src_l[e_i] = se;
      float e = sbuf[se * H + hd] + d_l[hd];
      e = fmaxf(e, 0.2f * e);
      alpha_l[e_i * H + hd] = __expf(e - m_l[hd]) * invden_l[hd];
    }
    __syncthreads();
    if (c0 < F) {
      for (int e_i = 0; e_i < ce; ++e_i) {
        int se = src_l[e_i];
        float al = alpha_l[e_i * H + myhead];
        const ushort_t* hp = hfeat + (size_t)se * F + c0;
        if (CPT == 4) {
          ushort4 v = *(const ushort4*)hp;
          acc[0] += al * bf2f(v.x); acc[1] += al * bf2f(v.y);
          acc[2] += al * bf2f(v.z); acc[3] += al * bf2f(v.w);
        } else {
          ushort2 v = *(const ushort2*)hp;
          acc[0] += al * bf2f(v.x); acc[1] += al * bf2f(v.y);
        }
      }
    }
    __syncthreads();
  }

  if (!MEAN_HEADS) {
    if (c0 < F) {
      const ushort_t* skip = (const ushort_t*)skip_v;
      ushort_t* out = (ushort_t*)out_v;
      ushort4 sv = *(const ushort4*)&skip[(size_t)node * F + c0];
      float sk[4] = {bf2f(sv.x), bf2f(sv.y), bf2f(sv.z), bf2f(sv.w)};
      ushort_t rr[CPT];
#pragma unroll
      for (int j = 0; j < CPT; ++j) {
        float xo = acc[j] + bias[c0 + j] + sk[j];
        if (ELU_OUT) xo = xo > 0.f ? xo : __expf(xo) - 1.f;
        rr[j] = f2bf(xo);
      }
      ushort4 o; o.x = rr[0]; o.y = rr[1]; o.z = rr[2]; o.w = rr[3];
      *(ushort4*)&out[(size_t)node * F + c0] = o;
    }
  } else {
    const float* skip = (const float*)skip_v;
    float* out = (float*)out_v;
    if (c0 < F) { accs[c0] = acc[0]; accs[c0 + 1] = acc[1]; }
    __syncthreads();
    if (t < C) {
      float sum = 0.f;
#pragma unroll
      for (int hd = 0; hd < H; ++hd) sum += accs[hd * C + t];
      out[(size_t)node * C + t] = sum * (1.f / (float)H) + bias[t] + skip[(size_t)node * C + t];
    }
  }
}

// ---------------------------------------------------------------- launch
extern "C" void kernel_launch(void* const* d_in, const int* in_sizes, int n_in,
                              void* d_out, int out_size, void* d_ws, size_t ws_size,
                              hipStream_t stream) {
  const float* x      = (const float*)d_in[0];
  const int*   ei     = (const int*)d_in[1];
  const float* W1     = (const float*)d_in[2];
  const float* a1s    = (const float*)d_in[3];
  const float* a1d    = (const float*)d_in[4];
  const float* b1     = (const float*)d_in[5];
  const float* lin1W  = (const float*)d_in[6];
  const float* lin1b  = (const float*)d_in[7];
  const float* W2     = (const float*)d_in[8];
  const float* a2s    = (const float*)d_in[9];
  const float* a2d    = (const float*)d_in[10];
  const float* b2     = (const float*)d_in[11];
  const float* lin2W  = (const float*)d_in[12];
  const float* lin2b  = (const float*)d_in[13];
  const float* W3     = (const float*)d_in[14];
  const float* a3s    = (const float*)d_in[15];
  const float* a3d    = (const float*)d_in[16];
  const float* b3     = (const float*)d_in[17];
  const float* lin3W  = (const float*)d_in[18];
  const float* lin3b  = (const float*)d_in[19];

  const int N = in_sizes[0] / 128;
  const int E = in_sizes[1] / 2;
  const int* src = ei;
  const int* dst = ei + E;

  char* ws = (char*)d_ws;
  size_t off = 0;
  auto alloc = [&](size_t bytes) -> void* {
    void* p = ws + off;
    off += (bytes + 255) & ~(size_t)255;
    return p;
  };
  ushort_t* h_bf    = (ushort_t*)alloc((size_t)N * 1024 * 2);
  ushort_t* skip_bf = (ushort_t*)alloc((size_t)N * 1024 * 2);
  float*    skip3   = (float*)alloc((size_t)N * 64 * 4);
  ushort_t* act_bf  = (ushort_t*)alloc((size_t)N * 1024 * 2);
  ushort_t* x_bf    = (ushort_t*)alloc((size_t)N * 128 * 2);
  ushort_t* W1cat   = (ushort_t*)alloc((size_t)2048 * 128 * 2);
  ushort_t* W2cat   = (ushort_t*)alloc((size_t)2048 * 1024 * 2);
  ushort_t* W3cat   = (ushort_t*)alloc((size_t)512 * 1024 * 2);
  float*    sd12    = (float*)alloc((size_t)4 * N * 4 * 4);
  float*    sb1 = sd12, *db1 = sd12 + N * 4, *sb2 = sd12 + 2 * N * 4, *db2 = sd12 + 3 * N * 4;
  float*    sb3     = (float*)alloc((size_t)N * 6 * 4);
  float*    db3     = (float*)alloc((size_t)N * 6 * 4);
  int*      indptr  = (int*)alloc((size_t)(N + 1) * 4);
  int*      cursor  = (int*)alloc((size_t)N * 4);
  int*      esrc    = (int*)alloc((size_t)(E + N) * 4);

  const int n4 = N * 128 / 4;
  prep_k<<<4006, 256, 0, stream>>>(x, x_bf, n4, W1, lin1W, W1cat, W2, lin2W, W2cat,
                                   W3, lin3W, W3cat, a3s, a3d);

  const int NZ = 4 * N * 4;
  init_k<<<(max(N, NZ) + 255) / 256, 256, 0, stream>>>(cursor, N, sd12, NZ);
  count_edges_k<<<(E + 255) / 256, 256, 0, stream>>>(dst, E, cursor);
  scan_k<<<1, 1024, 0, stream>>>(cursor, indptr, cursor, N);
  scatter_k<<<(E + N + 255) / 256, 256, 0, stream>>>(src, dst, E, N, cursor, esrc);

  const int MB  = (N + 127) / 128;
  const int MB3 = (N + 319) / 320;
  // ---- Layer 1 (K=128)
  gemm320<128, 1024, 1024, true><<<dim3(8, MB3), 1024, 0, stream>>>(
      x_bf, W1cat, lin1b, a1s, a1d, sb1, db1, h_bf, skip_bf, N);
  attn_k<4, 256, true, false><<<N, 256, 0, stream>>>(h_bf, sb1, db1, indptr, esrc, b1, skip_bf, act_bf);
  // ---- Layer 2 (K=1024)
  gemm320<1024, 1024, 1024, true><<<dim3(8, MB3), 1024, 0, stream>>>(
      act_bf, W2cat, lin2b, a2s, a2d, sb2, db2, h_bf, skip_bf, N);
  attn_k<4, 256, true, false><<<N, 256, 0, stream>>>(h_bf, sb2, db2, indptr, esrc, b2, skip_bf, act_bf);
  // ---- Layer 3 (128x128 ring; logits via folded cols 448..459)
  gemm_fused<512, 384, 64, true><<<dim3(4, MB), 256, 0, stream>>>(
      act_bf, W3cat, lin3b, sb3, db3, h_bf, skip3, N, 1024);
  attn_k<6, 64, false, true><<<N, 256, 0, stream>>>(h_bf, sb3, db3, indptr, esrc, b3, skip3, d_out);
}